// Round 1
// baseline (2431.884 us; speedup 1.0000x reference)
//
#include <hip/hip_runtime.h>
#include <math.h>

#define NG     32
#define NVARS  16384
#define NCLS   32768
#define NLITS  98304
#define FM_    128
#define QM_    32
#define NROUNDS 4

// ---------------- workspace layout (in floats) ----------------
#define OFF_VAR    ((size_t)0)           // 16384*128
#define OFF_CST    ((size_t)2097152)     // 32768*128
#define OFF_X      ((size_t)6291456)     // bufX: Xvq/Xcm/CD/Xug/UO (max 32768*160)
#define OFF_A      ((size_t)11534336)    // bufA: 32768*384
#define OFF_B      ((size_t)24117248)    // bufB: 32768*384
#define OFF_Q      ((size_t)36700160)    // 16384*32
#define OFF_CL     ((size_t)37224448)    // 32768*32
#define OFF_VG     ((size_t)38273024)    // 16384*32
#define OFF_LP     ((size_t)38797312)    // 16384*32
#define OFF_LN     ((size_t)39321600)    // 16384*32
#define OFF_CMEAN  ((size_t)39845888)    // 32*128
#define OFF_VMEAN  ((size_t)39849984)    // 32*128
#define OFF_PC     ((size_t)39854080)    // 32768
#define OFF_LOSS   ((size_t)39886848)    // 1

__device__ __forceinline__ float softplus_f(float x) {
  return fmaxf(x, 0.f) + log1pf(expf(-fabsf(x)));
}

// ---------------- init: variables & clause_state one-hot-ish ----------------
__global__ void init_state_kernel(float* __restrict__ var, float* __restrict__ cst) {
  int t = blockIdx.x * blockDim.x + threadIdx.x;
  const int total = (NVARS + NCLS) * FM_;
  if (t >= total) return;
  int row = t >> 7, m = t & 127;
  const float base = 2.82842712474619f; // sqrt(128)*0.25
  float val = ((m == 0) ? (1.f - 1.f / 128.f) : (-1.f / 128.f)) * base;
  if (row < NVARS) var[(size_t)row * FM_ + m] = val;
  else             cst[(size_t)(row - NVARS) * FM_ + m] = val;
}

// ---------------- concat builders ----------------
__global__ void build_xvq_kernel(const float* __restrict__ var, const float* __restrict__ noise,
                                 float* __restrict__ out) {
  int t = blockIdx.x * blockDim.x + threadIdx.x;
  const int total = NVARS * 132;
  if (t >= total) return;
  int v = t / 132, j = t - v * 132;
  out[t] = (j < 128) ? var[(size_t)v * 128 + j] : noise[(size_t)v * 4 + (j - 128)];
}

__global__ void build_xcm_kernel(const float* __restrict__ cst, const float* __restrict__ cl,
                                 float* __restrict__ out) {
  int t = blockIdx.x * blockDim.x + threadIdx.x;
  const int total = NCLS * 160;
  if (t >= total) return;
  int c = t / 160, j = t - c * 160;
  out[t] = (j < 128) ? cst[(size_t)c * 128 + j] : cl[(size_t)c * 32 + (j - 128)];
}

__global__ void build_xug_kernel(const float* __restrict__ var, const float* __restrict__ vg,
                                 const float* __restrict__ lp, const float* __restrict__ ln,
                                 float* __restrict__ out) {
  int t = blockIdx.x * blockDim.x + threadIdx.x;
  const int total = NVARS * 224;
  if (t >= total) return;
  int v = t / 224, j = t - v * 224;
  float x;
  if (j < 128)      x = var[(size_t)v * 128 + j];
  else if (j < 160) x = vg[(size_t)v * 32 + (j - 128)];
  else if (j < 192) x = lp[(size_t)v * 32 + (j - 160)];
  else              x = ln[(size_t)v * 32 + (j - 192)];
  out[t] = x;
}

// ---------------- fp32 tiled GEMM: C = act(A[MxK] @ W[KxN] + b) ----------------
template<bool RELU>
__global__ __launch_bounds__(256) void gemm_kernel(
    const float* __restrict__ A, const float* __restrict__ W,
    const float* __restrict__ bias, float* __restrict__ C,
    int M, int N, int K)
{
  __shared__ float As[16][64];
  __shared__ float Ws[16][64];
  const int bn = blockIdx.x * 64;
  const int bm = blockIdx.y * 64;
  const int tid = threadIdx.x;
  const int tx = tid & 15, ty = tid >> 4;
  const int arow = tid >> 2;            // 0..63
  const int akq  = (tid & 3) << 2;      // 0,4,8,12
  const int wk   = tid >> 4;            // 0..15
  const int wn   = (tid & 15) << 2;     // 0..60
  float acc[4][4] = {};

  for (int k0 = 0; k0 < K; k0 += 16) {
    // A tile (64 rows x 16 k)
    float4 av;
    const float* Ap = A + (size_t)(bm + arow) * K + k0 + akq;
    if (k0 + akq + 3 < K) {
      av = *(const float4*)Ap;
    } else {
      av.x = (k0 + akq + 0 < K) ? Ap[0] : 0.f;
      av.y = (k0 + akq + 1 < K) ? Ap[1] : 0.f;
      av.z = (k0 + akq + 2 < K) ? Ap[2] : 0.f;
      av.w = (k0 + akq + 3 < K) ? Ap[3] : 0.f;
    }
    As[akq + 0][arow] = av.x;
    As[akq + 1][arow] = av.y;
    As[akq + 2][arow] = av.z;
    As[akq + 3][arow] = av.w;
    // W tile (16 k x 64 n)
    float4 wv = make_float4(0.f, 0.f, 0.f, 0.f);
    if (k0 + wk < K) {
      const float* Wp = W + (size_t)(k0 + wk) * N + bn + wn;
      if (bn + wn + 3 < N) {
        wv = *(const float4*)Wp;
      } else {
        if (bn + wn + 0 < N) wv.x = Wp[0];
        if (bn + wn + 1 < N) wv.y = Wp[1];
        if (bn + wn + 2 < N) wv.z = Wp[2];
        if (bn + wn + 3 < N) wv.w = Wp[3];
      }
    }
    *(float4*)&Ws[wk][wn] = wv;
    __syncthreads();
    #pragma unroll
    for (int kk = 0; kk < 16; ++kk) {
      const float4 a = *(const float4*)&As[kk][ty << 2];
      const float4 w = *(const float4*)&Ws[kk][tx << 2];
      acc[0][0] += a.x * w.x; acc[0][1] += a.x * w.y; acc[0][2] += a.x * w.z; acc[0][3] += a.x * w.w;
      acc[1][0] += a.y * w.x; acc[1][1] += a.y * w.y; acc[1][2] += a.y * w.z; acc[1][3] += a.y * w.w;
      acc[2][0] += a.z * w.x; acc[2][1] += a.z * w.y; acc[2][2] += a.z * w.z; acc[2][3] += a.z * w.w;
      acc[3][0] += a.w * w.x; acc[3][1] += a.w * w.y; acc[3][2] += a.w * w.z; acc[3][3] += a.w * w.w;
    }
    __syncthreads();
  }
  #pragma unroll
  for (int i = 0; i < 4; ++i) {
    int row = bm + (ty << 2) + i;
    #pragma unroll
    for (int j = 0; j < 4; ++j) {
      int col = bn + (tx << 2) + j;
      if (col < N) {
        float v = acc[i][j] + bias[col];
        if (RELU) v = v > 0.f ? v : 0.2f * v;
        C[(size_t)row * N + col] = v;
      }
    }
  }
}

// ---------------- N=1 GEMM (vo last layer) ----------------
__global__ void gemm_n1_kernel(const float* __restrict__ A, const float* __restrict__ w,
                               const float* __restrict__ b, float* __restrict__ out) {
  int r = blockIdx.x * blockDim.x + threadIdx.x;
  if (r >= NVARS) return;
  const float4* a = (const float4*)(A + (size_t)r * 128);
  const float4* wv = (const float4*)w;
  float s = 0.f;
  #pragma unroll
  for (int i = 0; i < 32; ++i) {
    float4 x = a[i], y = wv[i];
    s += x.x * y.x + x.y * y.y + x.z * y.z + x.w * y.w;
  }
  out[r] = s + b[0];
}

// ---------------- clause_val over QM=32 channels ----------------
__global__ void clause_val_kernel(const float* __restrict__ Q, const int* __restrict__ lit_var,
                                  const int* __restrict__ lit_sign, float* __restrict__ cl) {
  int t = blockIdx.x * blockDim.x + threadIdx.x;
  if (t >= NCLS * 32) return;
  int c = t >> 5, m = t & 31;
  float s = 0.f;
  #pragma unroll
  for (int i = 0; i < 3; ++i) {
    int l = 3 * c + i;
    int v = lit_var[l];
    float sg = (float)lit_sign[l];
    float q = Q[(size_t)v * 32 + m];
    s += softplus_f(q * sg);
  }
  cl[t] = expf(-s);
}

// ---------------- d(sum cl)/dq scatter ----------------
__global__ void grad_scatter_kernel(const float* __restrict__ Q, const float* __restrict__ cl,
                                    const int* __restrict__ lit_var, const int* __restrict__ lit_sign,
                                    const int* __restrict__ lit_clause, float* __restrict__ vgrad) {
  int t = blockIdx.x * blockDim.x + threadIdx.x;
  if (t >= NLITS * 32) return;
  int l = t >> 5, m = t & 31;
  int v = lit_var[l];
  int c = lit_clause[l];
  int sgn = lit_sign[l];
  float q = Q[(size_t)v * 32 + m];
  float sig = 1.f / (1.f + expf(-q));
  float coef = sig - (sgn < 0 ? 1.f : 0.f);   // == sigmoid(q*s)*s
  float val = -cl[(size_t)c * 32 + m] * coef;
  atomicAdd(&vgrad[(size_t)v * 32 + m], val);
}

// ---------------- loss_pos / loss_neg scatter ----------------
__global__ void loss_scatter_kernel(const float* __restrict__ CD, const int* __restrict__ lit_var,
                                    const int* __restrict__ lit_sign, const int* __restrict__ lit_clause,
                                    float* __restrict__ lp, float* __restrict__ ln) {
  int t = blockIdx.x * blockDim.x + threadIdx.x;
  if (t >= NLITS * 32) return;
  int l = t >> 5, m = t & 31;
  int v = lit_var[l];
  int c = lit_clause[l];
  int sgn = lit_sign[l];
  float val = CD[(size_t)c * 160 + m];  // vloss = clause_data[:, :32]
  float* tgt = (sgn > 0) ? lp : ln;
  atomicAdd(&tgt[(size_t)v * 32 + m], val);
}

// ---------------- per-graph channel mean (partial sums, contiguous segments) ----------------
__global__ void seg_mean_kernel(const float* __restrict__ x, int stride, int coloff,
                                int rows_per_chunk, int rows_per_g, float inv_cnt,
                                float* __restrict__ out) {
  int g = blockIdx.x;
  int chunk = blockIdx.y;
  int m = threadIdx.x;  // 0..127
  int r0 = g * rows_per_g + chunk * rows_per_chunk;
  float s = 0.f;
  for (int r = 0; r < rows_per_chunk; ++r)
    s += x[(size_t)(r0 + r) * stride + coloff + m];
  atomicAdd(&out[g * 128 + m], s * inv_cnt);
}

// ---------------- pair_norm + state update (one wave per row) ----------------
__global__ __launch_bounds__(256) void pairnorm_update_kernel(
    const float* __restrict__ x, int stride, int coloff,
    const float* __restrict__ mean, float* __restrict__ state, int rows_per_g) {
  int wid = threadIdx.x >> 6;
  int lane = threadIdx.x & 63;
  int row = blockIdx.x * 4 + wid;
  int g = row / rows_per_g;
  const float* xp = x + (size_t)row * stride + coloff;
  float y0 = xp[lane]      - mean[g * 128 + lane];
  float y1 = xp[lane + 64] - mean[g * 128 + lane + 64];
  float ss = y0 * y0 + y1 * y1;
  #pragma unroll
  for (int o = 32; o > 0; o >>= 1) ss += __shfl_xor(ss, o);
  float inv = rsqrtf(ss * (1.f / 128.f) + 1e-6f);
  float* sp = state + (size_t)row * 128;
  sp[lane]      = y0 * inv * 0.25f + 0.1f * sp[lane];
  sp[lane + 64] = y1 * inv * 0.25f + 0.1f * sp[lane + 64];
}

// ---------------- per-clause satisfaction value + loss term ----------------
__global__ void per_clause_kernel(const float* __restrict__ logits, const int* __restrict__ lit_var,
                                  const int* __restrict__ lit_sign, float* __restrict__ pc) {
  int c = blockIdx.x * blockDim.x + threadIdx.x;
  if (c >= NCLS) return;
  float s = 0.f;
  #pragma unroll
  for (int i = 0; i < 3; ++i) {
    int l = 3 * c + i;
    int v = lit_var[l];
    float sg = (float)lit_sign[l];
    s += softplus_f(logits[v] * sg);
  }
  float vv = expf(-s);
  pc[c] = vv * (-logf(1.f - vv + 1e-8f));
}

// ---------------- per-graph loss reduce: sqrt(sum + eps) -> atomicAdd ----------------
__global__ __launch_bounds__(256) void graph_loss_kernel(const float* __restrict__ pc,
                                                         float* __restrict__ loss_acc) {
  __shared__ float sm[256];
  int g = blockIdx.x;
  float s = 0.f;
  for (int i = threadIdx.x; i < 1024; i += 256) s += pc[(size_t)g * 1024 + i];
  sm[threadIdx.x] = s;
  __syncthreads();
  for (int o = 128; o > 0; o >>= 1) {
    if (threadIdx.x < o) sm[threadIdx.x] += sm[threadIdx.x + o];
    __syncthreads();
  }
  if (threadIdx.x == 0) atomicAdd(loss_acc, sqrtf(sm[0] + 1e-6f));
}

__global__ void finalize_kernel(const float* __restrict__ loss_acc, float* __restrict__ out) {
  out[0] = loss_acc[0] * 0.25f;
}

// =======================================================================
extern "C" void kernel_launch(void* const* d_in, const int* in_sizes, int n_in,
                              void* d_out, int out_size, void* d_ws, size_t ws_size,
                              hipStream_t stream) {
  const int* lit_var    = (const int*)d_in[0];
  const int* lit_sign   = (const int*)d_in[1];
  const int* lit_clause = (const int*)d_in[2];
  const float* noise    = (const float*)d_in[5];
  const float* vq_w0 = (const float*)d_in[6];   const float* vq_b0 = (const float*)d_in[7];
  const float* vq_w1 = (const float*)d_in[8];   const float* vq_b1 = (const float*)d_in[9];
  const float* vq_w2 = (const float*)d_in[10];  const float* vq_b2 = (const float*)d_in[11];
  const float* cm_w0 = (const float*)d_in[12];  const float* cm_b0 = (const float*)d_in[13];
  const float* cm_w1 = (const float*)d_in[14];  const float* cm_b1 = (const float*)d_in[15];
  const float* cm_w2 = (const float*)d_in[16];  const float* cm_b2 = (const float*)d_in[17];
  const float* ug_w0 = (const float*)d_in[18];  const float* ug_b0 = (const float*)d_in[19];
  const float* ug_w1 = (const float*)d_in[20];  const float* ug_b1 = (const float*)d_in[21];
  const float* ug_w2 = (const float*)d_in[22];  const float* ug_b2 = (const float*)d_in[23];
  const float* vo_w0 = (const float*)d_in[24];  const float* vo_b0 = (const float*)d_in[25];
  const float* vo_w1 = (const float*)d_in[26];  const float* vo_b1 = (const float*)d_in[27];
  const float* vo_w2 = (const float*)d_in[28];  const float* vo_b2 = (const float*)d_in[29];

  float* ws = (float*)d_ws;
  float* var   = ws + OFF_VAR;
  float* cst   = ws + OFF_CST;
  float* bufX  = ws + OFF_X;
  float* bufA  = ws + OFF_A;
  float* bufB  = ws + OFF_B;
  float* Q     = ws + OFF_Q;
  float* cl    = ws + OFF_CL;
  float* vg    = ws + OFF_VG;
  float* lp    = ws + OFF_LP;
  float* ln    = ws + OFF_LN;
  float* cmean = ws + OFF_CMEAN;
  float* vmean = ws + OFF_VMEAN;
  float* pc    = ws + OFF_PC;
  float* loss  = ws + OFF_LOSS;
  float* logits = (float*)d_out;         // d_out[0..16383] doubles as logits buffer
  float* loss_out = (float*)d_out + NVARS;

  // init states + zero loss accumulator
  init_state_kernel<<<(NVARS + NCLS) * FM_ / 256, 256, 0, stream>>>(var, cst);
  hipMemsetAsync(loss, 0, sizeof(float), stream);

  for (int r = 0; r < NROUNDS; ++r) {
    const float* noise_r = noise + (size_t)r * NVARS * 4;

    // ---- vq MLP: query ----
    build_xvq_kernel<<<NVARS * 132 / 256, 256, 0, stream>>>(var, noise_r, bufX);
    gemm_kernel<true ><<<dim3(1, NVARS / 64), 256, 0, stream>>>(bufX, vq_w0, vq_b0, bufA, NVARS, 64, 132);
    gemm_kernel<true ><<<dim3(1, NVARS / 64), 256, 0, stream>>>(bufA, vq_w1, vq_b1, bufB, NVARS, 64, 64);
    gemm_kernel<false><<<dim3(1, NVARS / 64), 256, 0, stream>>>(bufB, vq_w2, vq_b2, Q, NVARS, 32, 64);

    // ---- clause_val(Q) + grad ----
    clause_val_kernel<<<NCLS * 32 / 256, 256, 0, stream>>>(Q, lit_var, lit_sign, cl);
    hipMemsetAsync(vg, 0, (size_t)NVARS * 32 * sizeof(float), stream);
    grad_scatter_kernel<<<NLITS * 32 / 256, 256, 0, stream>>>(Q, cl, lit_var, lit_sign, lit_clause, vg);

    // ---- cm MLP: clause_data ----
    build_xcm_kernel<<<NCLS * 160 / 256, 256, 0, stream>>>(cst, cl, bufX);
    gemm_kernel<true ><<<dim3(6, NCLS / 64), 256, 0, stream>>>(bufX, cm_w0, cm_b0, bufA, NCLS, 384, 160);
    gemm_kernel<true ><<<dim3(6, NCLS / 64), 256, 0, stream>>>(bufA, cm_w1, cm_b1, bufB, NCLS, 384, 384);
    gemm_kernel<false><<<dim3(3, NCLS / 64), 256, 0, stream>>>(bufB, cm_w2, cm_b2, bufX, NCLS, 160, 384);
    // bufX now holds clause_data (CD)

    // ---- clause_state = pair_norm(CD[:,32:])*0.25 + 0.1*clause_state ----
    hipMemsetAsync(cmean, 0, 32 * 128 * sizeof(float), stream);
    seg_mean_kernel<<<dim3(32, 8), 128, 0, stream>>>(bufX, 160, 32, 128, 1024, 1.f / 1024.f, cmean);
    pairnorm_update_kernel<<<NCLS / 4, 256, 0, stream>>>(bufX, 160, 32, cmean, cst, 1024);

    // ---- loss_pos / loss_neg from vloss = CD[:, :32] ----
    hipMemsetAsync(lp, 0, (size_t)NVARS * 32 * sizeof(float), stream);
    hipMemsetAsync(ln, 0, (size_t)NVARS * 32 * sizeof(float), stream);
    loss_scatter_kernel<<<NLITS * 32 / 256, 256, 0, stream>>>(bufX, lit_var, lit_sign, lit_clause, lp, ln);

    // ---- ug MLP + variables update ----
    build_xug_kernel<<<NVARS * 224 / 256, 256, 0, stream>>>(var, vg, lp, ln, bufX);
    gemm_kernel<true ><<<dim3(4, NVARS / 64), 256, 0, stream>>>(bufX, ug_w0, ug_b0, bufA, NVARS, 256, 224);
    gemm_kernel<true ><<<dim3(4, NVARS / 64), 256, 0, stream>>>(bufA, ug_w1, ug_b1, bufB, NVARS, 256, 256);
    gemm_kernel<false><<<dim3(2, NVARS / 64), 256, 0, stream>>>(bufB, ug_w2, ug_b2, bufX, NVARS, 128, 256);
    hipMemsetAsync(vmean, 0, 32 * 128 * sizeof(float), stream);
    seg_mean_kernel<<<dim3(32, 4), 128, 0, stream>>>(bufX, 128, 0, 128, 512, 1.f / 512.f, vmean);
    pairnorm_update_kernel<<<NVARS / 4, 256, 0, stream>>>(bufX, 128, 0, vmean, var, 512);

    // ---- vo MLP -> logits ----
    gemm_kernel<true ><<<dim3(2, NVARS / 64), 256, 0, stream>>>(var, vo_w0, vo_b0, bufA, NVARS, 128, 128);
    gemm_kernel<true ><<<dim3(2, NVARS / 64), 256, 0, stream>>>(bufA, vo_w1, vo_b1, bufB, NVARS, 128, 128);
    gemm_n1_kernel<<<NVARS / 256, 256, 0, stream>>>(bufB, vo_w2, vo_b2, logits);

    // ---- logit loss ----
    per_clause_kernel<<<NCLS / 256, 256, 0, stream>>>(logits, lit_var, lit_sign, pc);
    graph_loss_kernel<<<NG, 256, 0, stream>>>(pc, loss);
  }

  finalize_kernel<<<1, 1, 0, stream>>>(loss, loss_out);
}

// Round 2
// 1217.390 us; speedup vs baseline: 1.9976x; 1.9976x over previous
//
#include <hip/hip_runtime.h>
#include <hip/hip_bf16.h>
#include <math.h>

#define NG     32
#define NVARS  16384
#define NCLS   32768
#define NLITS  98304
#define NROUNDS 4

typedef __attribute__((ext_vector_type(8))) short bf16x8;
typedef __attribute__((ext_vector_type(4))) float f32x4;

// ---------------- workspace layout (float units) ----------------
#define OFF_VAR    ((size_t)0)            // f32 16384x128
#define OFF_CST    ((size_t)2097152)      // f32 32768x128
#define OFF_XCMB   ((size_t)6291456)      // bf16 32768x192
#define OFF_XUGB   ((size_t)9437184)      // bf16 16384x256
#define OFF_ABUF   ((size_t)11534336)     // bf16 32768x384
#define OFF_BBUF   ((size_t)17825792)     // bf16 32768x384
#define OFF_CD     ((size_t)24117248)     // f32 32768x192 (also UO 16384x128)
#define OFF_XF     ((size_t)30408704)     // f32 16384x132 (Xvq, vo1 out)
#define OFF_H1     ((size_t)32571392)     // f32 16384x64
#define OFF_H2     ((size_t)33619968)     // f32 16384x64
#define OFF_Q      ((size_t)34668544)     // f32 16384x32
#define OFF_CL     ((size_t)35192832)     // f32 32768x32
#define OFF_VG     ((size_t)36241408)     // f32 16384x32
#define OFF_LP     ((size_t)36765696)     // f32 16384x32
#define OFF_LN     ((size_t)37289984)     // f32 16384x32
#define OFF_CMEAN  ((size_t)37814272)     // f32 32x128
#define OFF_VMEAN  ((size_t)37818368)     // f32 32x128
#define OFF_PC     ((size_t)37822464)     // f32 32768
#define OFF_LOSS   ((size_t)37855232)     // f32 1
#define OFF_WT     ((size_t)37855236)     // bf16 pool 491520 elems

// Wt sub-offsets (bf16 elements within WT pool)
#define WT_CM0  ((size_t)0)       // 384x192
#define WT_CM1  ((size_t)73728)   // 384x384
#define WT_CM2  ((size_t)221184)  // 192x384
#define WT_UG0  ((size_t)294912)  // 256x256
#define WT_UG1  ((size_t)360448)  // 256x256
#define WT_UG2  ((size_t)425984)  // 128x256
#define WT_VO0  ((size_t)458752)  // 128x128
#define WT_VO1  ((size_t)475136)  // 128x128

__device__ __forceinline__ float softplus_f(float x) {
  return fmaxf(x, 0.f) + log1pf(expf(-fabsf(x)));
}
__device__ __forceinline__ short f2bf(float x) {
  __hip_bfloat16 h = __float2bfloat16(x);
  return *reinterpret_cast<short*>(&h);
}
__device__ __forceinline__ float bf2f(short s) {
  __hip_bfloat16 h = *reinterpret_cast<__hip_bfloat16*>(&s);
  return __bfloat162float(h);
}

// ---------------- init: states (f32 + bf16 copies into concat buffers) ----------------
__global__ void init_state_kernel(float* __restrict__ var, float* __restrict__ cst,
                                  short* __restrict__ xugb, short* __restrict__ xcmb) {
  int t = blockIdx.x * blockDim.x + threadIdx.x;
  const int total = (NVARS + NCLS) * 128;
  if (t >= total) return;
  int row = t >> 7, m = t & 127;
  const float base = 2.82842712474619f; // sqrt(128)*0.25
  float val = ((m == 0) ? (1.f - 1.f / 128.f) : (-1.f / 128.f)) * base;
  if (row < NVARS) {
    var[(size_t)row * 128 + m] = val;
    xugb[(size_t)row * 256 + m] = f2bf(val);
  } else {
    int c = row - NVARS;
    cst[(size_t)c * 128 + m] = val;
    xcmb[(size_t)c * 192 + m] = f2bf(val);
  }
}

// ---------------- weight convert + transpose + pad: Wt[n][k] = W[k][n] ----------------
__global__ void convert_wt_kernel(const float* __restrict__ W, int K, int N,
                                  short* __restrict__ Wt, int Kp, int Np) {
  int t = blockIdx.x * blockDim.x + threadIdx.x;
  if (t >= Np * Kp) return;
  int n = t / Kp, k = t - n * Kp;
  float v = (n < N && k < K) ? W[(size_t)k * N + n] : 0.f;
  Wt[t] = f2bf(v);
}

// ---------------- concat builders ----------------
__global__ void build_xvq_kernel(const float* __restrict__ var, const float* __restrict__ noise,
                                 float* __restrict__ out) {
  int t = blockIdx.x * blockDim.x + threadIdx.x;
  const int total = NVARS * 132;
  if (t >= total) return;
  int v = t / 132, j = t - v * 132;
  out[t] = (j < 128) ? var[(size_t)v * 128 + j] : noise[(size_t)v * 4 + (j - 128)];
}

// XcmB cols 128..191: bf16(cl) then zero pad
__global__ void xcm_tail_kernel(const float* __restrict__ cl, short* __restrict__ xcmb) {
  int t = blockIdx.x * blockDim.x + threadIdx.x;
  if (t >= NCLS * 64) return;
  int c = t >> 6, j = t & 63;
  xcmb[(size_t)c * 192 + 128 + j] = (j < 32) ? f2bf(cl[(size_t)c * 32 + j]) : (short)0;
}

// XugB cols 128..255: vg, lp, ln, zero-pad
__global__ void xug_tail_kernel(const float* __restrict__ vg, const float* __restrict__ lp,
                                const float* __restrict__ ln, short* __restrict__ xugb) {
  int t = blockIdx.x * blockDim.x + threadIdx.x;
  if (t >= NVARS * 128) return;
  int v = t >> 7, j = t & 127;
  float x;
  if (j < 32)       x = vg[(size_t)v * 32 + j];
  else if (j < 64)  x = lp[(size_t)v * 32 + (j - 32)];
  else if (j < 96)  x = ln[(size_t)v * 32 + (j - 64)];
  else { xugb[(size_t)v * 256 + 128 + j] = (short)0; return; }
  xugb[(size_t)v * 256 + 128 + j] = f2bf(x);
}

// ---------------- bf16 MFMA GEMM: C = act(A[MxK] @ Wt^T + b) ----------------
// A: bf16 [M x lda], uses cols [0,Kp). Wt: bf16 [Np x Kp] (pre-transposed weights).
// Tile: 128(M) x 64(N), BK=64, 4 waves (2M x 2N), global_load_lds 16B staging.
template<bool RELU, bool OUTBF16>
__global__ __launch_bounds__(256) void gemm_mfma_kernel(
    const short* __restrict__ A, int lda,
    const short* __restrict__ Wt,
    const float* __restrict__ bias, int nbias,
    void* __restrict__ Cout, int Np, int Kp)
{
  __shared__ short As[128 * 64];  // [row][k]
  __shared__ short Bs[64 * 64];   // [n][k]
  const int bn = blockIdx.x * 64;
  const int bm = blockIdx.y * 128;
  const int tid  = threadIdx.x;
  const int wid  = tid >> 6;
  const int lane = tid & 63;
  const int wm = (wid >> 1) * 64;   // wave M offset in tile
  const int wn = (wid & 1) * 32;    // wave N offset in tile

  f32x4 acc[4][2] = {};

  for (int k0 = 0; k0 < Kp; k0 += 64) {
    // stage A tile: 128 rows x 64 k = 16KB = 4 insts/wave
    #pragma unroll
    for (int i = 0; i < 4; ++i) {
      int s = (i * 4 + wid) * 64 + lane;          // 16B slot
      int row = s >> 3, cs = (s & 7) << 3;        // 8 shorts per slot
      const short* src = A + (size_t)(bm + row) * lda + k0 + cs;
      __builtin_amdgcn_global_load_lds(
          (const __attribute__((address_space(1))) void*)src,
          (__attribute__((address_space(3))) void*)(As + (size_t)(i * 4 + wid) * 64 * 8),
          16, 0, 0);
    }
    // stage B tile: 64 n x 64 k = 8KB = 2 insts/wave
    #pragma unroll
    for (int i = 0; i < 2; ++i) {
      int s = (i * 4 + wid) * 64 + lane;
      int n = s >> 3, cs = (s & 7) << 3;
      const short* src = Wt + (size_t)(bn + n) * Kp + k0 + cs;
      __builtin_amdgcn_global_load_lds(
          (const __attribute__((address_space(1))) void*)src,
          (__attribute__((address_space(3))) void*)(Bs + (size_t)(i * 4 + wid) * 64 * 8),
          16, 0, 0);
    }
    __syncthreads();   // drains vmcnt before barrier (compiler-inserted)

    #pragma unroll
    for (int ks = 0; ks < 2; ++ks) {
      const int kof = ks * 32 + (lane >> 4) * 8;
      bf16x8 a[4], b[2];
      #pragma unroll
      for (int mi = 0; mi < 4; ++mi)
        a[mi] = *(const bf16x8*)&As[(wm + mi * 16 + (lane & 15)) * 64 + kof];
      #pragma unroll
      for (int ni = 0; ni < 2; ++ni)
        b[ni] = *(const bf16x8*)&Bs[(wn + ni * 16 + (lane & 15)) * 64 + kof];
      #pragma unroll
      for (int mi = 0; mi < 4; ++mi)
        #pragma unroll
        for (int ni = 0; ni < 2; ++ni)
          acc[mi][ni] = __builtin_amdgcn_mfma_f32_16x16x32_bf16(a[mi], b[ni], acc[mi][ni], 0, 0, 0);
    }
    __syncthreads();
  }

  // epilogue: C/D layout col=lane&15, row=(lane>>4)*4+reg
  const int col0 = bn + wn + (lane & 15);
  const int row0 = bm + wm + (lane >> 4) * 4;
  #pragma unroll
  for (int ni = 0; ni < 2; ++ni) {
    int col = col0 + ni * 16;
    float bv = (col < nbias) ? bias[col] : 0.f;
    #pragma unroll
    for (int mi = 0; mi < 4; ++mi) {
      #pragma unroll
      for (int j = 0; j < 4; ++j) {
        int row = row0 + mi * 16 + j;
        float v = acc[mi][ni][j] + bv;
        if (RELU) v = v > 0.f ? v : 0.2f * v;
        if (OUTBF16) ((short*)Cout)[(size_t)row * Np + col] = f2bf(v);
        else        ((float*)Cout)[(size_t)row * Np + col] = v;
      }
    }
  }
}

// ---------------- fp32 tiled GEMM (vq only) ----------------
template<bool RELU>
__global__ __launch_bounds__(256) void gemm_kernel(
    const float* __restrict__ A, const float* __restrict__ W,
    const float* __restrict__ bias, float* __restrict__ C,
    int M, int N, int K)
{
  __shared__ float As[16][64];
  __shared__ float Ws[16][64];
  const int bn = blockIdx.x * 64;
  const int bm = blockIdx.y * 64;
  const int tid = threadIdx.x;
  const int tx = tid & 15, ty = tid >> 4;
  const int arow = tid >> 2;
  const int akq  = (tid & 3) << 2;
  const int wk   = tid >> 4;
  const int wn   = (tid & 15) << 2;
  float acc[4][4] = {};

  for (int k0 = 0; k0 < K; k0 += 16) {
    float4 av;
    const float* Ap = A + (size_t)(bm + arow) * K + k0 + akq;
    if (k0 + akq + 3 < K) {
      av = *(const float4*)Ap;
    } else {
      av.x = (k0 + akq + 0 < K) ? Ap[0] : 0.f;
      av.y = (k0 + akq + 1 < K) ? Ap[1] : 0.f;
      av.z = (k0 + akq + 2 < K) ? Ap[2] : 0.f;
      av.w = (k0 + akq + 3 < K) ? Ap[3] : 0.f;
    }
    As[akq + 0][arow] = av.x;
    As[akq + 1][arow] = av.y;
    As[akq + 2][arow] = av.z;
    As[akq + 3][arow] = av.w;
    float4 wv = make_float4(0.f, 0.f, 0.f, 0.f);
    if (k0 + wk < K) {
      const float* Wp = W + (size_t)(k0 + wk) * N + bn + wn;
      if (bn + wn + 3 < N) wv = *(const float4*)Wp;
      else {
        if (bn + wn + 0 < N) wv.x = Wp[0];
        if (bn + wn + 1 < N) wv.y = Wp[1];
        if (bn + wn + 2 < N) wv.z = Wp[2];
        if (bn + wn + 3 < N) wv.w = Wp[3];
      }
    }
    *(float4*)&Ws[wk][wn] = wv;
    __syncthreads();
    #pragma unroll
    for (int kk = 0; kk < 16; ++kk) {
      const float4 a = *(const float4*)&As[kk][ty << 2];
      const float4 w = *(const float4*)&Ws[kk][tx << 2];
      acc[0][0] += a.x * w.x; acc[0][1] += a.x * w.y; acc[0][2] += a.x * w.z; acc[0][3] += a.x * w.w;
      acc[1][0] += a.y * w.x; acc[1][1] += a.y * w.y; acc[1][2] += a.y * w.z; acc[1][3] += a.y * w.w;
      acc[2][0] += a.z * w.x; acc[2][1] += a.z * w.y; acc[2][2] += a.z * w.z; acc[2][3] += a.z * w.w;
      acc[3][0] += a.w * w.x; acc[3][1] += a.w * w.y; acc[3][2] += a.w * w.z; acc[3][3] += a.w * w.w;
    }
    __syncthreads();
  }
  #pragma unroll
  for (int i = 0; i < 4; ++i) {
    int row = bm + (ty << 2) + i;
    #pragma unroll
    for (int j = 0; j < 4; ++j) {
      int col = bn + (tx << 2) + j;
      if (col < N) {
        float v = acc[i][j] + bias[col];
        if (RELU) v = v > 0.f ? v : 0.2f * v;
        C[(size_t)row * N + col] = v;
      }
    }
  }
}

// ---------------- N=1 GEMM (vo last layer) ----------------
__global__ void gemm_n1_kernel(const float* __restrict__ A, const float* __restrict__ w,
                               const float* __restrict__ b, float* __restrict__ out) {
  int r = blockIdx.x * blockDim.x + threadIdx.x;
  if (r >= NVARS) return;
  const float4* a = (const float4*)(A + (size_t)r * 128);
  const float4* wv = (const float4*)w;
  float s = 0.f;
  #pragma unroll
  for (int i = 0; i < 32; ++i) {
    float4 x = a[i], y = wv[i];
    s += x.x * y.x + x.y * y.y + x.z * y.z + x.w * y.w;
  }
  out[r] = s + b[0];
}

// ---------------- clause_val over QM=32 channels ----------------
__global__ void clause_val_kernel(const float* __restrict__ Q, const int* __restrict__ lit_var,
                                  const int* __restrict__ lit_sign, float* __restrict__ cl) {
  int t = blockIdx.x * blockDim.x + threadIdx.x;
  if (t >= NCLS * 32) return;
  int c = t >> 5, m = t & 31;
  float s = 0.f;
  #pragma unroll
  for (int i = 0; i < 3; ++i) {
    int l = 3 * c + i;
    int v = lit_var[l];
    float sg = (float)lit_sign[l];
    float q = Q[(size_t)v * 32 + m];
    s += softplus_f(q * sg);
  }
  cl[t] = expf(-s);
}

// ---------------- d(sum cl)/dq scatter ----------------
__global__ void grad_scatter_kernel(const float* __restrict__ Q, const float* __restrict__ cl,
                                    const int* __restrict__ lit_var, const int* __restrict__ lit_sign,
                                    const int* __restrict__ lit_clause, float* __restrict__ vgrad) {
  int t = blockIdx.x * blockDim.x + threadIdx.x;
  if (t >= NLITS * 32) return;
  int l = t >> 5, m = t & 31;
  int v = lit_var[l];
  int c = lit_clause[l];
  int sgn = lit_sign[l];
  float q = Q[(size_t)v * 32 + m];
  float sig = 1.f / (1.f + expf(-q));
  float coef = sig - (sgn < 0 ? 1.f : 0.f);
  float val = -cl[(size_t)c * 32 + m] * coef;
  atomicAdd(&vgrad[(size_t)v * 32 + m], val);
}

// ---------------- loss_pos / loss_neg scatter (CD stride 192) ----------------
__global__ void loss_scatter_kernel(const float* __restrict__ CD, const int* __restrict__ lit_var,
                                    const int* __restrict__ lit_sign, const int* __restrict__ lit_clause,
                                    float* __restrict__ lp, float* __restrict__ ln) {
  int t = blockIdx.x * blockDim.x + threadIdx.x;
  if (t >= NLITS * 32) return;
  int l = t >> 5, m = t & 31;
  int v = lit_var[l];
  int c = lit_clause[l];
  int sgn = lit_sign[l];
  float val = CD[(size_t)c * 192 + m];
  float* tgt = (sgn > 0) ? lp : ln;
  atomicAdd(&tgt[(size_t)v * 32 + m], val);
}

// ---------------- per-graph channel mean ----------------
__global__ void seg_mean_kernel(const float* __restrict__ x, int stride, int coloff,
                                int rows_per_chunk, int rows_per_g, float inv_cnt,
                                float* __restrict__ out) {
  int g = blockIdx.x;
  int chunk = blockIdx.y;
  int m = threadIdx.x;
  int r0 = g * rows_per_g + chunk * rows_per_chunk;
  float s = 0.f;
  for (int r = 0; r < rows_per_chunk; ++r)
    s += x[(size_t)(r0 + r) * stride + coloff + m];
  atomicAdd(&out[g * 128 + m], s * inv_cnt);
}

// ---------------- pair_norm + state update + bf16 copy ----------------
__global__ __launch_bounds__(256) void pairnorm_update_kernel(
    const float* __restrict__ x, int stride, int coloff,
    const float* __restrict__ mean, float* __restrict__ state,
    short* __restrict__ bout, int bstride, int rows_per_g) {
  int wid = threadIdx.x >> 6;
  int lane = threadIdx.x & 63;
  int row = blockIdx.x * 4 + wid;
  int g = row / rows_per_g;
  const float* xp = x + (size_t)row * stride + coloff;
  float y0 = xp[lane]      - mean[g * 128 + lane];
  float y1 = xp[lane + 64] - mean[g * 128 + lane + 64];
  float ss = y0 * y0 + y1 * y1;
  #pragma unroll
  for (int o = 32; o > 0; o >>= 1) ss += __shfl_xor(ss, o);
  float inv = rsqrtf(ss * (1.f / 128.f) + 1e-6f);
  float* sp = state + (size_t)row * 128;
  float s0 = y0 * inv * 0.25f + 0.1f * sp[lane];
  float s1 = y1 * inv * 0.25f + 0.1f * sp[lane + 64];
  sp[lane]      = s0;
  sp[lane + 64] = s1;
  bout[(size_t)row * bstride + lane]      = f2bf(s0);
  bout[(size_t)row * bstride + lane + 64] = f2bf(s1);
}

// ---------------- per-clause loss term ----------------
__global__ void per_clause_kernel(const float* __restrict__ logits, const int* __restrict__ lit_var,
                                  const int* __restrict__ lit_sign, float* __restrict__ pc) {
  int c = blockIdx.x * blockDim.x + threadIdx.x;
  if (c >= NCLS) return;
  float s = 0.f;
  #pragma unroll
  for (int i = 0; i < 3; ++i) {
    int l = 3 * c + i;
    int v = lit_var[l];
    float sg = (float)lit_sign[l];
    s += softplus_f(logits[v] * sg);
  }
  float vv = expf(-s);
  pc[c] = vv * (-logf(1.f - vv + 1e-8f));
}

__global__ __launch_bounds__(256) void graph_loss_kernel(const float* __restrict__ pc,
                                                         float* __restrict__ loss_acc) {
  __shared__ float sm[256];
  int g = blockIdx.x;
  float s = 0.f;
  for (int i = threadIdx.x; i < 1024; i += 256) s += pc[(size_t)g * 1024 + i];
  sm[threadIdx.x] = s;
  __syncthreads();
  for (int o = 128; o > 0; o >>= 1) {
    if (threadIdx.x < o) sm[threadIdx.x] += sm[threadIdx.x + o];
    __syncthreads();
  }
  if (threadIdx.x == 0) atomicAdd(loss_acc, sqrtf(sm[0] + 1e-6f));
}

__global__ void finalize_kernel(const float* __restrict__ loss_acc, float* __restrict__ out) {
  out[0] = loss_acc[0] * 0.25f;
}

// =======================================================================
extern "C" void kernel_launch(void* const* d_in, const int* in_sizes, int n_in,
                              void* d_out, int out_size, void* d_ws, size_t ws_size,
                              hipStream_t stream) {
  const int* lit_var    = (const int*)d_in[0];
  const int* lit_sign   = (const int*)d_in[1];
  const int* lit_clause = (const int*)d_in[2];
  const float* noise    = (const float*)d_in[5];
  const float* vq_w0 = (const float*)d_in[6];   const float* vq_b0 = (const float*)d_in[7];
  const float* vq_w1 = (const float*)d_in[8];   const float* vq_b1 = (const float*)d_in[9];
  const float* vq_w2 = (const float*)d_in[10];  const float* vq_b2 = (const float*)d_in[11];
  const float* cm_w0 = (const float*)d_in[12];  const float* cm_b0 = (const float*)d_in[13];
  const float* cm_w1 = (const float*)d_in[14];  const float* cm_b1 = (const float*)d_in[15];
  const float* cm_w2 = (const float*)d_in[16];  const float* cm_b2 = (const float*)d_in[17];
  const float* ug_w0 = (const float*)d_in[18];  const float* ug_b0 = (const float*)d_in[19];
  const float* ug_w1 = (const float*)d_in[20];  const float* ug_b1 = (const float*)d_in[21];
  const float* ug_w2 = (const float*)d_in[22];  const float* ug_b2 = (const float*)d_in[23];
  const float* vo_w0 = (const float*)d_in[24];  const float* vo_b0 = (const float*)d_in[25];
  const float* vo_w1 = (const float*)d_in[26];  const float* vo_b1 = (const float*)d_in[27];
  const float* vo_w2 = (const float*)d_in[28];  const float* vo_b2 = (const float*)d_in[29];

  float* ws = (float*)d_ws;
  float* var   = ws + OFF_VAR;
  float* cst   = ws + OFF_CST;
  short* xcmb  = (short*)(ws + OFF_XCMB);
  short* xugb  = (short*)(ws + OFF_XUGB);
  short* bufA  = (short*)(ws + OFF_ABUF);
  short* bufB  = (short*)(ws + OFF_BBUF);
  float* CD    = ws + OFF_CD;     // also UO (16384x128) after loss_scatter
  float* XF    = ws + OFF_XF;     // Xvq f32, later vo1 out f32
  float* H1    = ws + OFF_H1;
  float* H2    = ws + OFF_H2;
  float* Q     = ws + OFF_Q;
  float* cl    = ws + OFF_CL;
  float* vg    = ws + OFF_VG;
  float* lp    = ws + OFF_LP;
  float* ln    = ws + OFF_LN;
  float* cmean = ws + OFF_CMEAN;
  float* vmean = ws + OFF_VMEAN;
  float* pc    = ws + OFF_PC;
  float* loss  = ws + OFF_LOSS;
  short* wt    = (short*)(ws + OFF_WT);
  float* logits = (float*)d_out;
  float* loss_out = (float*)d_out + NVARS;

  // weight convert+transpose+pad (bf16)
  {
    struct { const float* W; int K, N; size_t off; int Kp, Np; } cv[8] = {
      {cm_w0, 160, 384, WT_CM0, 192, 384},
      {cm_w1, 384, 384, WT_CM1, 384, 384},
      {cm_w2, 384, 160, WT_CM2, 384, 192},
      {ug_w0, 224, 256, WT_UG0, 256, 256},
      {ug_w1, 256, 256, WT_UG1, 256, 256},
      {ug_w2, 256, 128, WT_UG2, 256, 128},
      {vo_w0, 128, 128, WT_VO0, 128, 128},
      {vo_w1, 128, 128, WT_VO1, 128, 128},
    };
    for (int i = 0; i < 8; ++i)
      convert_wt_kernel<<<(cv[i].Kp * cv[i].Np + 255) / 256, 256, 0, stream>>>(
          cv[i].W, cv[i].K, cv[i].N, wt + cv[i].off, cv[i].Kp, cv[i].Np);
  }

  init_state_kernel<<<(NVARS + NCLS) * 128 / 256, 256, 0, stream>>>(var, cst, xugb, xcmb);
  hipMemsetAsync(loss, 0, sizeof(float), stream);

  for (int r = 0; r < NROUNDS; ++r) {
    const float* noise_r = noise + (size_t)r * NVARS * 4;

    // ---- vq MLP (fp32): query ----
    build_xvq_kernel<<<NVARS * 132 / 256, 256, 0, stream>>>(var, noise_r, XF);
    gemm_kernel<true ><<<dim3(1, NVARS / 64), 256, 0, stream>>>(XF, vq_w0, vq_b0, H1, NVARS, 64, 132);
    gemm_kernel<true ><<<dim3(1, NVARS / 64), 256, 0, stream>>>(H1, vq_w1, vq_b1, H2, NVARS, 64, 64);
    gemm_kernel<false><<<dim3(1, NVARS / 64), 256, 0, stream>>>(H2, vq_w2, vq_b2, Q, NVARS, 32, 64);

    // ---- clause_val(Q) + grad scatter ----
    clause_val_kernel<<<NCLS * 32 / 256, 256, 0, stream>>>(Q, lit_var, lit_sign, cl);
    hipMemsetAsync(vg, 0, (size_t)NVARS * 32 * sizeof(float), stream);
    grad_scatter_kernel<<<NLITS * 32 / 256, 256, 0, stream>>>(Q, cl, lit_var, lit_sign, lit_clause, vg);

    // ---- cm MLP (bf16 MFMA) ----
    xcm_tail_kernel<<<NCLS * 64 / 256, 256, 0, stream>>>(cl, xcmb);
    gemm_mfma_kernel<true , true ><<<dim3(6, NCLS / 128), 256, 0, stream>>>(xcmb, 192, wt + WT_CM0, cm_b0, 384, bufA, 384, 192);
    gemm_mfma_kernel<true , true ><<<dim3(6, NCLS / 128), 256, 0, stream>>>(bufA, 384, wt + WT_CM1, cm_b1, 384, bufB, 384, 384);
    gemm_mfma_kernel<false, false><<<dim3(3, NCLS / 128), 256, 0, stream>>>(bufB, 384, wt + WT_CM2, cm_b2, 160, CD, 192, 384);

    // ---- clause_state pair_norm update (writes cst f32 + bf16 into xcmb) ----
    hipMemsetAsync(cmean, 0, 32 * 128 * sizeof(float), stream);
    seg_mean_kernel<<<dim3(32, 8), 128, 0, stream>>>(CD, 192, 32, 128, 1024, 1.f / 1024.f, cmean);
    pairnorm_update_kernel<<<NCLS / 4, 256, 0, stream>>>(CD, 192, 32, cmean, cst, xcmb, 192, 1024);

    // ---- loss_pos / loss_neg scatter from CD[:, :32] ----
    hipMemsetAsync(lp, 0, (size_t)NVARS * 32 * sizeof(float), stream);
    hipMemsetAsync(ln, 0, (size_t)NVARS * 32 * sizeof(float), stream);
    loss_scatter_kernel<<<NLITS * 32 / 256, 256, 0, stream>>>(CD, lit_var, lit_sign, lit_clause, lp, ln);

    // ---- ug MLP (bf16 MFMA) + variables update ----
    xug_tail_kernel<<<NVARS * 128 / 256, 256, 0, stream>>>(vg, lp, ln, xugb);
    gemm_mfma_kernel<true , true ><<<dim3(4, NVARS / 128), 256, 0, stream>>>(xugb, 256, wt + WT_UG0, ug_b0, 256, bufA, 256, 256);
    gemm_mfma_kernel<true , true ><<<dim3(4, NVARS / 128), 256, 0, stream>>>(bufA, 256, wt + WT_UG1, ug_b1, 256, bufB, 256, 256);
    gemm_mfma_kernel<false, false><<<dim3(2, NVARS / 128), 256, 0, stream>>>(bufB, 256, wt + WT_UG2, ug_b2, 128, CD, 128, 256);
    hipMemsetAsync(vmean, 0, 32 * 128 * sizeof(float), stream);
    seg_mean_kernel<<<dim3(32, 4), 128, 0, stream>>>(CD, 128, 0, 128, 512, 1.f / 512.f, vmean);
    pairnorm_update_kernel<<<NVARS / 4, 256, 0, stream>>>(CD, 128, 0, vmean, var, xugb, 256, 512);

    // ---- vo MLP (bf16 MFMA, A = updated var bf16 in xugb[:, :128]) ----
    gemm_mfma_kernel<true , true ><<<dim3(2, NVARS / 128), 256, 0, stream>>>(xugb, 256, wt + WT_VO0, vo_b0, 128, bufA, 128, 128);
    gemm_mfma_kernel<true , false><<<dim3(2, NVARS / 128), 256, 0, stream>>>(bufA, 128, wt + WT_VO1, vo_b1, 128, XF, 128, 128);
    gemm_n1_kernel<<<NVARS / 256, 256, 0, stream>>>(XF, vo_w2, vo_b2, logits);

    // ---- logit loss ----
    per_clause_kernel<<<NCLS / 256, 256, 0, stream>>>(logits, lit_var, lit_sign, pc);
    graph_loss_kernel<<<NG, 256, 0, stream>>>(pc, loss);
  }

  finalize_kernel<<<1, 1, 0, stream>>>(loss, loss_out);
}

// Round 3
// 721.939 us; speedup vs baseline: 3.3685x; 1.6863x over previous
//
#include <hip/hip_runtime.h>
#include <hip/hip_bf16.h>
#include <math.h>

#define NG     32
#define NVARS  16384
#define NCLS   32768
#define NLITS  98304
#define NROUNDS 4

typedef __attribute__((ext_vector_type(8))) short bf16x8;
typedef __attribute__((ext_vector_type(4))) float f32x4;

// ---------------- workspace layout (float units) ----------------
#define OFF_VAR    ((size_t)0)            // f32 16384x128
#define OFF_CST    ((size_t)2097152)      // f32 32768x128
#define OFF_XCMB   ((size_t)6291456)      // bf16 32768x192
#define OFF_XUGB   ((size_t)9437184)      // bf16 16384x256
#define OFF_ABUF   ((size_t)11534336)     // bf16 32768x384
#define OFF_BBUF   ((size_t)17825792)     // bf16 32768x384
#define OFF_CD     ((size_t)24117248)     // f32 32768x192 (also UO 16384x128)
#define OFF_Q      ((size_t)30408704)     // f32 16384x32
// zero block (one memset per round covers all of these, contiguous):
#define OFF_VG     ((size_t)30932992)     // f32 16384x32
#define OFF_LP     ((size_t)31457280)     // f32 16384x32
#define OFF_LN     ((size_t)31981568)     // f32 16384x32
#define OFF_CMEAN  ((size_t)32505856)     // f32 32x128
#define OFF_VMEAN  ((size_t)32509952)     // f32 32x128
#define ZERO_FLOATS ((size_t)1581056)
#define OFF_LOSS   ((size_t)32514048)     // f32 1
#define OFF_WT     ((size_t)32514052)     // bf16 pool 507904 elems

// Wt sub-offsets (bf16 elements within WT pool)
#define WT_CM0  ((size_t)0)       // [384][192]
#define WT_CM1  ((size_t)73728)   // [384][384]
#define WT_CM2  ((size_t)221184)  // [192][384]
#define WT_UG0  ((size_t)294912)  // [256][256]
#define WT_UG1  ((size_t)360448)  // [256][256]
#define WT_UG2  ((size_t)425984)  // [128][256]
#define WT_VO0  ((size_t)458752)  // [128][128]
#define WT_VO1  ((size_t)475136)  // [128][128]
#define WT_VQ0  ((size_t)491520)  // [64][160]
#define WT_VQ1  ((size_t)501760)  // [64][64]
#define WT_VQ2  ((size_t)505856)  // [32][64]

__device__ __forceinline__ float softplus_f(float x) {
  return fmaxf(x, 0.f) + log1pf(expf(-fabsf(x)));
}
__device__ __forceinline__ short f2bf(float x) {
  __hip_bfloat16 h = __float2bfloat16(x);
  return *reinterpret_cast<short*>(&h);
}
__device__ __forceinline__ float bf2f(short s) {
  __hip_bfloat16 h = *reinterpret_cast<__hip_bfloat16*>(&s);
  return __bfloat162float(h);
}

// ---------------- init: states + constant pads + loss=0 ----------------
__global__ void init_state_kernel(float* __restrict__ var, float* __restrict__ cst,
                                  short* __restrict__ xugb, short* __restrict__ xcmb,
                                  float* __restrict__ loss) {
  int t = blockIdx.x * blockDim.x + threadIdx.x;
  if (t == 0) *loss = 0.f;
  const int main_total = (NVARS + NCLS) * 128;
  if (t < main_total) {
    int row = t >> 7, m = t & 127;
    const float base = 2.82842712474619f; // sqrt(128)*0.25
    float val = ((m == 0) ? (1.f - 1.f / 128.f) : (-1.f / 128.f)) * base;
    if (row < NVARS) {
      var[(size_t)row * 128 + m] = val;
      xugb[(size_t)row * 256 + m] = f2bf(val);
    } else {
      int c = row - NVARS;
      cst[(size_t)c * 128 + m] = val;
      xcmb[(size_t)c * 192 + m] = f2bf(val);
    }
    return;
  }
  int t2 = t - main_total;
  if (t2 < NVARS * 32) {           // xugb cols 224..255 = 0 (forever)
    int row = t2 >> 5, j = t2 & 31;
    xugb[(size_t)row * 256 + 224 + j] = 0;
    return;
  }
  int t3 = t2 - NVARS * 32;
  if (t3 < NCLS * 32) {            // xcmb cols 160..191 = 0 (forever)
    int row = t3 >> 5, j = t3 & 31;
    xcmb[(size_t)row * 192 + 160 + j] = 0;
  }
}

// ---------------- one-shot weight convert+transpose+pad ----------------
__global__ void convert_all_kernel(
    const float* __restrict__ cm_w0, const float* __restrict__ cm_w1, const float* __restrict__ cm_w2,
    const float* __restrict__ ug_w0, const float* __restrict__ ug_w1, const float* __restrict__ ug_w2,
    const float* __restrict__ vo_w0, const float* __restrict__ vo_w1,
    const float* __restrict__ vq_w0, const float* __restrict__ vq_w1, const float* __restrict__ vq_w2,
    short* __restrict__ wt) {
  int t = blockIdx.x * blockDim.x + threadIdx.x;
  const float* W; int K, N, Kp; size_t base; int idx;
  if      (t < 73728)  { W = cm_w0; K = 160; N = 384; Kp = 192; base = WT_CM0; idx = t; }
  else if (t < 221184) { W = cm_w1; K = 384; N = 384; Kp = 384; base = WT_CM1; idx = t - 73728; }
  else if (t < 294912) { W = cm_w2; K = 384; N = 160; Kp = 384; base = WT_CM2; idx = t - 221184; }
  else if (t < 360448) { W = ug_w0; K = 224; N = 256; Kp = 256; base = WT_UG0; idx = t - 294912; }
  else if (t < 425984) { W = ug_w1; K = 256; N = 256; Kp = 256; base = WT_UG1; idx = t - 360448; }
  else if (t < 458752) { W = ug_w2; K = 256; N = 128; Kp = 256; base = WT_UG2; idx = t - 425984; }
  else if (t < 475136) { W = vo_w0; K = 128; N = 128; Kp = 128; base = WT_VO0; idx = t - 458752; }
  else if (t < 491520) { W = vo_w1; K = 128; N = 128; Kp = 128; base = WT_VO1; idx = t - 475136; }
  else if (t < 501760) { W = vq_w0; K = 132; N = 64;  Kp = 160; base = WT_VQ0; idx = t - 491520; }
  else if (t < 505856) { W = vq_w1; K = 64;  N = 64;  Kp = 64;  base = WT_VQ1; idx = t - 501760; }
  else if (t < 507904) { W = vq_w2; K = 64;  N = 32;  Kp = 64;  base = WT_VQ2; idx = t - 505856; }
  else return;
  int n = idx / Kp, k = idx - n * Kp;
  float v = (k < K && n < N) ? W[(size_t)k * N + n] : 0.f;
  wt[base + idx] = f2bf(v);
}

// ---------------- fused vq MLP: xugb[:, :128] (+noise) -> Q f32 ----------------
// 64 rows/block, 4 waves, each wave owns 16 rows through all layers. No barriers.
__global__ __launch_bounds__(256) void fused_vq_kernel(
    const short* __restrict__ xugb, const float* __restrict__ noise,
    const short* __restrict__ w0, const short* __restrict__ w1, const short* __restrict__ w2,
    const float* __restrict__ b0, const float* __restrict__ b1, const float* __restrict__ b2,
    float* __restrict__ Q) {
  __shared__ short A[64 * 160];
  __shared__ short H1[4][16 * 64];
  __shared__ short H2[4][16 * 64];
  const int wid = threadIdx.x >> 6, lane = threadIdx.x & 63;
  const int rbase = blockIdx.x * 64 + wid * 16;
  // stage wave's 16 rows, cols 0..127 from xugb
  #pragma unroll
  for (int i = 0; i < 4; ++i) {
    int s = i * 64 + lane;            // 0..255
    int row = s >> 4, c8 = s & 15;
    *(bf16x8*)&A[(wid * 16 + row) * 160 + c8 * 8] =
        *(const bf16x8*)&xugb[(size_t)(rbase + row) * 256 + c8 * 8];
  }
  // tail cols 128..159: 4 noise + zero pad
  {
    int row = lane >> 2, seg = lane & 3;
    bf16x8 z = {0, 0, 0, 0, 0, 0, 0, 0};
    if (seg == 0) {
      float4 nz = *(const float4*)&noise[(size_t)(rbase + row) * 4];
      z[0] = f2bf(nz.x); z[1] = f2bf(nz.y); z[2] = f2bf(nz.z); z[3] = f2bf(nz.w);
    }
    *(bf16x8*)&A[(wid * 16 + row) * 160 + 128 + seg * 8] = z;
  }
  const int kof = (lane >> 4) * 8;
  const int l15 = lane & 15;
  // layer0: K=160, N=64
  f32x4 acc[4] = {};
  #pragma unroll
  for (int ks = 0; ks < 5; ++ks) {
    bf16x8 a = *(const bf16x8*)&A[(wid * 16 + l15) * 160 + ks * 32 + kof];
    #pragma unroll
    for (int ni = 0; ni < 4; ++ni) {
      bf16x8 b = *(const bf16x8*)&w0[(ni * 16 + l15) * 160 + ks * 32 + kof];
      acc[ni] = __builtin_amdgcn_mfma_f32_16x16x32_bf16(a, b, acc[ni], 0, 0, 0);
    }
  }
  #pragma unroll
  for (int ni = 0; ni < 4; ++ni) {
    int col = ni * 16 + l15;
    float bb = b0[col];
    #pragma unroll
    for (int j = 0; j < 4; ++j) {
      float v = acc[ni][j] + bb; v = v > 0.f ? v : 0.2f * v;
      H1[wid][((lane >> 4) * 4 + j) * 64 + col] = f2bf(v);
    }
  }
  // layer1: K=64, N=64
  f32x4 acc2[4] = {};
  #pragma unroll
  for (int ks = 0; ks < 2; ++ks) {
    bf16x8 a = *(const bf16x8*)&H1[wid][l15 * 64 + ks * 32 + kof];
    #pragma unroll
    for (int ni = 0; ni < 4; ++ni) {
      bf16x8 b = *(const bf16x8*)&w1[(ni * 16 + l15) * 64 + ks * 32 + kof];
      acc2[ni] = __builtin_amdgcn_mfma_f32_16x16x32_bf16(a, b, acc2[ni], 0, 0, 0);
    }
  }
  #pragma unroll
  for (int ni = 0; ni < 4; ++ni) {
    int col = ni * 16 + l15;
    float bb = b1[col];
    #pragma unroll
    for (int j = 0; j < 4; ++j) {
      float v = acc2[ni][j] + bb; v = v > 0.f ? v : 0.2f * v;
      H2[wid][((lane >> 4) * 4 + j) * 64 + col] = f2bf(v);
    }
  }
  // layer2: K=64, N=32
  f32x4 acc3[2] = {};
  #pragma unroll
  for (int ks = 0; ks < 2; ++ks) {
    bf16x8 a = *(const bf16x8*)&H2[wid][l15 * 64 + ks * 32 + kof];
    #pragma unroll
    for (int ni = 0; ni < 2; ++ni) {
      bf16x8 b = *(const bf16x8*)&w2[(ni * 16 + l15) * 64 + ks * 32 + kof];
      acc3[ni] = __builtin_amdgcn_mfma_f32_16x16x32_bf16(a, b, acc3[ni], 0, 0, 0);
    }
  }
  #pragma unroll
  for (int ni = 0; ni < 2; ++ni) {
    int col = ni * 16 + l15;
    float bb = b2[col];
    #pragma unroll
    for (int j = 0; j < 4; ++j)
      Q[(size_t)(rbase + (lane >> 4) * 4 + j) * 32 + col] = acc3[ni][j] + bb;
  }
}

// ---------------- fused clause_val + bf16 tail + grad scatter ----------------
__global__ void fused_clause_kernel(const float* __restrict__ Q, const int* __restrict__ lit_var,
                                    const int* __restrict__ lit_sign,
                                    short* __restrict__ xcmb, float* __restrict__ vg) {
  int t = blockIdx.x * blockDim.x + threadIdx.x;
  if (t >= NCLS * 32) return;
  int c = t >> 5, m = t & 31;
  int l0 = 3 * c;
  int v0 = lit_var[l0], v1 = lit_var[l0 + 1], v2 = lit_var[l0 + 2];
  int s0 = lit_sign[l0], s1 = lit_sign[l0 + 1], s2 = lit_sign[l0 + 2];
  float q0 = Q[(size_t)v0 * 32 + m];
  float q1 = Q[(size_t)v1 * 32 + m];
  float q2 = Q[(size_t)v2 * 32 + m];
  float sp = softplus_f(q0 * (float)s0) + softplus_f(q1 * (float)s1) + softplus_f(q2 * (float)s2);
  float cl = expf(-sp);
  xcmb[(size_t)c * 192 + 128 + m] = f2bf(cl);
  float g0 = 1.f / (1.f + expf(-q0)) - (s0 < 0 ? 1.f : 0.f);
  float g1 = 1.f / (1.f + expf(-q1)) - (s1 < 0 ? 1.f : 0.f);
  float g2 = 1.f / (1.f + expf(-q2)) - (s2 < 0 ? 1.f : 0.f);
  atomicAdd(&vg[(size_t)v0 * 32 + m], -cl * g0);
  atomicAdd(&vg[(size_t)v1 * 32 + m], -cl * g1);
  atomicAdd(&vg[(size_t)v2 * 32 + m], -cl * g2);
}

// ---------------- bf16 MFMA GEMM with optional fused epilogue ----------------
// EPI 0: plain (RELU/OUTBF16). EPI 1: cm2 (f32 out cols 32..159, vloss scatter, cmean).
// EPI 2: ug2 (f32 out all cols, vmean).
template<bool RELU, bool OUTBF16, int EPI>
__global__ __launch_bounds__(256) void gemm_mfma_kernel(
    const short* __restrict__ A, int lda,
    const short* __restrict__ Wt,
    const float* __restrict__ bias, int nbias,
    void* __restrict__ Cout, int Np, int Kp,
    const int* __restrict__ lit_var, const int* __restrict__ lit_sign,
    float* __restrict__ lp, float* __restrict__ ln,
    float* __restrict__ meanbuf, float inv_cnt, int gshift) {
  __shared__ short As[128 * 64];
  __shared__ short Bs[64 * 64];
  const int bn = blockIdx.x * 64;
  const int bm = blockIdx.y * 128;
  const int tid  = threadIdx.x;
  const int wid  = tid >> 6;
  const int lane = tid & 63;
  const int wm = (wid >> 1) * 64;
  const int wn = (wid & 1) * 32;

  f32x4 acc[4][2] = {};

  for (int k0 = 0; k0 < Kp; k0 += 64) {
    #pragma unroll
    for (int i = 0; i < 4; ++i) {
      int s = (i * 4 + wid) * 64 + lane;
      int row = s >> 3, cs = (s & 7) << 3;
      const short* src = A + (size_t)(bm + row) * lda + k0 + cs;
      __builtin_amdgcn_global_load_lds(
          (const __attribute__((address_space(1))) void*)src,
          (__attribute__((address_space(3))) void*)(As + (size_t)(i * 4 + wid) * 64 * 8),
          16, 0, 0);
    }
    #pragma unroll
    for (int i = 0; i < 2; ++i) {
      int s = (i * 4 + wid) * 64 + lane;
      int n = s >> 3, cs = (s & 7) << 3;
      const short* src = Wt + (size_t)(bn + n) * Kp + k0 + cs;
      __builtin_amdgcn_global_load_lds(
          (const __attribute__((address_space(1))) void*)src,
          (__attribute__((address_space(3))) void*)(Bs + (size_t)(i * 4 + wid) * 64 * 8),
          16, 0, 0);
    }
    __syncthreads();

    #pragma unroll
    for (int ks = 0; ks < 2; ++ks) {
      const int kof = ks * 32 + (lane >> 4) * 8;
      bf16x8 a[4], b[2];
      #pragma unroll
      for (int mi = 0; mi < 4; ++mi)
        a[mi] = *(const bf16x8*)&As[(wm + mi * 16 + (lane & 15)) * 64 + kof];
      #pragma unroll
      for (int ni = 0; ni < 2; ++ni)
        b[ni] = *(const bf16x8*)&Bs[(wn + ni * 16 + (lane & 15)) * 64 + kof];
      #pragma unroll
      for (int mi = 0; mi < 4; ++mi)
        #pragma unroll
        for (int ni = 0; ni < 2; ++ni)
          acc[mi][ni] = __builtin_amdgcn_mfma_f32_16x16x32_bf16(a[mi], b[ni], acc[mi][ni], 0, 0, 0);
    }
    __syncthreads();
  }

  const int col0 = bn + wn + (lane & 15);
  const int row0 = bm + wm + (lane >> 4) * 4;
  #pragma unroll
  for (int ni = 0; ni < 2; ++ni) {
    int col = col0 + ni * 16;
    float bv = (col < nbias) ? bias[col] : 0.f;
    float colsum = 0.f;
    #pragma unroll
    for (int mi = 0; mi < 4; ++mi) {
      #pragma unroll
      for (int j = 0; j < 4; ++j) {
        int row = row0 + mi * 16 + j;
        float v = acc[mi][ni][j] + bv;
        if (EPI == 0) {
          if (RELU) v = v > 0.f ? v : 0.2f * v;
          if (OUTBF16) ((short*)Cout)[(size_t)row * Np + col] = f2bf(v);
          else         ((float*)Cout)[(size_t)row * Np + col] = v;
        } else if (EPI == 1) {
          if (col < 32) {
            #pragma unroll
            for (int i = 0; i < 3; ++i) {
              int l = 3 * row + i;
              int vv = lit_var[l];
              float* tgt = (lit_sign[l] > 0) ? lp : ln;
              atomicAdd(&tgt[(size_t)vv * 32 + col], v);
            }
          } else if (col < 160) {
            ((float*)Cout)[(size_t)row * Np + col] = v;
            colsum += v;
          }
        } else { // EPI == 2
          ((float*)Cout)[(size_t)row * Np + col] = v;
          colsum += v;
        }
      }
    }
    if ((EPI == 1 && col >= 32 && col < 160) || EPI == 2) {
      colsum += __shfl_xor(colsum, 16);
      colsum += __shfl_xor(colsum, 32);
      if ((lane >> 4) == 0) {
        int midx = (EPI == 1) ? (col - 32) : col;
        atomicAdd(&meanbuf[(size_t)(bm >> gshift) * 128 + midx], colsum * inv_cnt);
      }
    }
  }
}

// ---------------- pair_norm + state update + bf16 copy ----------------
__global__ __launch_bounds__(256) void pairnorm_update_kernel(
    const float* __restrict__ x, int stride, int coloff,
    const float* __restrict__ mean, float* __restrict__ state,
    short* __restrict__ bout, int bstride, int rows_per_g) {
  int wid = threadIdx.x >> 6;
  int lane = threadIdx.x & 63;
  int row = blockIdx.x * 4 + wid;
  int g = row / rows_per_g;
  const float* xp = x + (size_t)row * stride + coloff;
  float y0 = xp[lane]      - mean[g * 128 + lane];
  float y1 = xp[lane + 64] - mean[g * 128 + lane + 64];
  float ss = y0 * y0 + y1 * y1;
  #pragma unroll
  for (int o = 32; o > 0; o >>= 1) ss += __shfl_xor(ss, o);
  float inv = rsqrtf(ss * (1.f / 128.f) + 1e-6f);
  float* sp = state + (size_t)row * 128;
  float s0 = y0 * inv * 0.25f + 0.1f * sp[lane];
  float s1 = y1 * inv * 0.25f + 0.1f * sp[lane + 64];
  sp[lane]      = s0;
  sp[lane + 64] = s1;
  bout[(size_t)row * bstride + lane]      = f2bf(s0);
  bout[(size_t)row * bstride + lane + 64] = f2bf(s1);
}

// ---------------- vg/lp/ln -> xugb bf16 cols 128..223 ----------------
__global__ void xug_tail_kernel(const float* __restrict__ vg, const float* __restrict__ lp,
                                const float* __restrict__ ln, short* __restrict__ xugb) {
  int t = blockIdx.x * blockDim.x + threadIdx.x;
  if (t >= NVARS * 128) return;
  int v = t >> 7, j = t & 127;
  if (j >= 96) return;  // cols 224..255 init-zeroed
  float x;
  if (j < 32)       x = vg[(size_t)v * 32 + j];
  else if (j < 64)  x = lp[(size_t)v * 32 + (j - 32)];
  else              x = ln[(size_t)v * 32 + (j - 64)];
  xugb[(size_t)v * 256 + 128 + j] = f2bf(x);
}

// ---------------- fused vo MLP: xugb[:, :128] -> logits f32 ----------------
__global__ __launch_bounds__(256) void fused_vo_kernel(
    const short* __restrict__ xugb,
    const short* __restrict__ w0, const short* __restrict__ w1,
    const float* __restrict__ b0, const float* __restrict__ b1,
    const float* __restrict__ w2, const float* __restrict__ b2,
    float* __restrict__ logits) {
  __shared__ short A[64 * 128];
  __shared__ short H1[4][16 * 128];
  __shared__ short H2[4][16 * 128];
  const int wid = threadIdx.x >> 6, lane = threadIdx.x & 63;
  const int rbase = blockIdx.x * 64 + wid * 16;
  #pragma unroll
  for (int i = 0; i < 4; ++i) {
    int s = i * 64 + lane;
    int row = s >> 4, c8 = s & 15;
    *(bf16x8*)&A[(wid * 16 + row) * 128 + c8 * 8] =
        *(const bf16x8*)&xugb[(size_t)(rbase + row) * 256 + c8 * 8];
  }
  const int kof = (lane >> 4) * 8;
  const int l15 = lane & 15;
  // layer0: K=128, N=128
  f32x4 acc[8] = {};
  #pragma unroll
  for (int ks = 0; ks < 4; ++ks) {
    bf16x8 a = *(const bf16x8*)&A[(wid * 16 + l15) * 128 + ks * 32 + kof];
    #pragma unroll
    for (int ni = 0; ni < 8; ++ni) {
      bf16x8 b = *(const bf16x8*)&w0[(ni * 16 + l15) * 128 + ks * 32 + kof];
      acc[ni] = __builtin_amdgcn_mfma_f32_16x16x32_bf16(a, b, acc[ni], 0, 0, 0);
    }
  }
  #pragma unroll
  for (int ni = 0; ni < 8; ++ni) {
    int col = ni * 16 + l15;
    float bb = b0[col];
    #pragma unroll
    for (int j = 0; j < 4; ++j) {
      float v = acc[ni][j] + bb; v = v > 0.f ? v : 0.2f * v;
      H1[wid][((lane >> 4) * 4 + j) * 128 + col] = f2bf(v);
    }
  }
  // layer1: K=128, N=128
  f32x4 acc2[8] = {};
  #pragma unroll
  for (int ks = 0; ks < 4; ++ks) {
    bf16x8 a = *(const bf16x8*)&H1[wid][l15 * 128 + ks * 32 + kof];
    #pragma unroll
    for (int ni = 0; ni < 8; ++ni) {
      bf16x8 b = *(const bf16x8*)&w1[(ni * 16 + l15) * 128 + ks * 32 + kof];
      acc2[ni] = __builtin_amdgcn_mfma_f32_16x16x32_bf16(a, b, acc2[ni], 0, 0, 0);
    }
  }
  #pragma unroll
  for (int ni = 0; ni < 8; ++ni) {
    int col = ni * 16 + l15;
    float bb = b1[col];
    #pragma unroll
    for (int j = 0; j < 4; ++j) {
      float v = acc2[ni][j] + bb; v = v > 0.f ? v : 0.2f * v;
      H2[wid][((lane >> 4) * 4 + j) * 128 + col] = f2bf(v);
    }
  }
  // final dot: row = lane>>2, quarter q = lane&3 covers 32 elems
  {
    int row = lane >> 2, q = lane & 3;
    float s = 0.f;
    #pragma unroll
    for (int jj = 0; jj < 4; ++jj) {
      bf16x8 h = *(const bf16x8*)&H2[wid][row * 128 + q * 32 + jj * 8];
      #pragma unroll
      for (int e = 0; e < 8; ++e) s += bf2f(h[e]) * w2[q * 32 + jj * 8 + e];
    }
    s += __shfl_xor(s, 1);
    s += __shfl_xor(s, 2);
    if (q == 0) logits[rbase + row] = s + b2[0];
  }
}

// ---------------- fused per-clause loss + per-graph sqrt reduce ----------------
__global__ __launch_bounds__(1024) void fused_loss_kernel(
    const float* __restrict__ logits, const int* __restrict__ lit_var,
    const int* __restrict__ lit_sign, float* __restrict__ loss) {
  __shared__ float lg[512];
  __shared__ float red[16];
  int g = blockIdx.x, tid = threadIdx.x;
  if (tid < 512) lg[tid] = logits[(size_t)g * 512 + tid];
  __syncthreads();
  int c = g * 1024 + tid;
  float s = 0.f;
  #pragma unroll
  for (int i = 0; i < 3; ++i) {
    int l = 3 * c + i;
    float sg = (float)lit_sign[l];
    s += softplus_f(lg[lit_var[l] - g * 512] * sg);
  }
  float vv = expf(-s);
  float pcv = vv * (-logf(1.f - vv + 1e-8f));
  #pragma unroll
  for (int o = 32; o > 0; o >>= 1) pcv += __shfl_xor(pcv, o);
  if ((tid & 63) == 0) red[tid >> 6] = pcv;
  __syncthreads();
  if (tid < 16) {
    float x = red[tid];
    #pragma unroll
    for (int o = 8; o > 0; o >>= 1) x += __shfl_xor(x, o);
    if (tid == 0) atomicAdd(loss, sqrtf(x + 1e-6f));
  }
}

__global__ void finalize_kernel(const float* __restrict__ loss_acc, float* __restrict__ out) {
  out[0] = loss_acc[0] * 0.25f;
}

// =======================================================================
extern "C" void kernel_launch(void* const* d_in, const int* in_sizes, int n_in,
                              void* d_out, int out_size, void* d_ws, size_t ws_size,
                              hipStream_t stream) {
  const int* lit_var    = (const int*)d_in[0];
  const int* lit_sign   = (const int*)d_in[1];
  const float* noise    = (const float*)d_in[5];
  const float* vq_w0 = (const float*)d_in[6];   const float* vq_b0 = (const float*)d_in[7];
  const float* vq_w1 = (const float*)d_in[8];   const float* vq_b1 = (const float*)d_in[9];
  const float* vq_w2 = (const float*)d_in[10];  const float* vq_b2 = (const float*)d_in[11];
  const float* cm_w0 = (const float*)d_in[12];  const float* cm_b0 = (const float*)d_in[13];
  const float* cm_w1 = (const float*)d_in[14];  const float* cm_b1 = (const float*)d_in[15];
  const float* cm_w2 = (const float*)d_in[16];  const float* cm_b2 = (const float*)d_in[17];
  const float* ug_w0 = (const float*)d_in[18];  const float* ug_b0 = (const float*)d_in[19];
  const float* ug_w1 = (const float*)d_in[20];  const float* ug_b1 = (const float*)d_in[21];
  const float* ug_w2 = (const float*)d_in[22];  const float* ug_b2 = (const float*)d_in[23];
  const float* vo_w0 = (const float*)d_in[24];  const float* vo_b0 = (const float*)d_in[25];
  const float* vo_w1 = (const float*)d_in[26];  const float* vo_b1 = (const float*)d_in[27];
  const float* vo_w2 = (const float*)d_in[28];  const float* vo_b2 = (const float*)d_in[29];

  float* ws = (float*)d_ws;
  float* var   = ws + OFF_VAR;
  float* cst   = ws + OFF_CST;
  short* xcmb  = (short*)(ws + OFF_XCMB);
  short* xugb  = (short*)(ws + OFF_XUGB);
  short* bufA  = (short*)(ws + OFF_ABUF);
  short* bufB  = (short*)(ws + OFF_BBUF);
  float* CD    = ws + OFF_CD;
  float* Q     = ws + OFF_Q;
  float* vg    = ws + OFF_VG;
  float* lp    = ws + OFF_LP;
  float* ln    = ws + OFF_LN;
  float* cmean = ws + OFF_CMEAN;
  float* vmean = ws + OFF_VMEAN;
  float* loss  = ws + OFF_LOSS;
  short* wt    = (short*)(ws + OFF_WT);
  float* logits = (float*)d_out;
  float* loss_out = (float*)d_out + NVARS;

  convert_all_kernel<<<1984, 256, 0, stream>>>(cm_w0, cm_w1, cm_w2, ug_w0, ug_w1, ug_w2,
                                               vo_w0, vo_w1, vq_w0, vq_w1, vq_w2, wt);
  init_state_kernel<<<30720, 256, 0, stream>>>(var, cst, xugb, xcmb, loss);

  for (int r = 0; r < NROUNDS; ++r) {
    const float* noise_r = noise + (size_t)r * NVARS * 4;

    hipMemsetAsync(ws + OFF_VG, 0, ZERO_FLOATS * sizeof(float), stream);

    // vq MLP -> Q
    fused_vq_kernel<<<NVARS / 64, 256, 0, stream>>>(
        xugb, noise_r, wt + WT_VQ0, wt + WT_VQ1, wt + WT_VQ2, vq_b0, vq_b1, vq_b2, Q);

    // clause_val + xcmb tail + grad scatter
    fused_clause_kernel<<<NCLS * 32 / 256, 256, 0, stream>>>(Q, lit_var, lit_sign, xcmb, vg);

    // cm MLP
    gemm_mfma_kernel<true, true, 0><<<dim3(6, NCLS / 128), 256, 0, stream>>>(
        xcmb, 192, wt + WT_CM0, cm_b0, 384, bufA, 384, 192,
        nullptr, nullptr, nullptr, nullptr, nullptr, 0.f, 0);
    gemm_mfma_kernel<true, true, 0><<<dim3(6, NCLS / 128), 256, 0, stream>>>(
        bufA, 384, wt + WT_CM1, cm_b1, 384, bufB, 384, 384,
        nullptr, nullptr, nullptr, nullptr, nullptr, 0.f, 0);
    gemm_mfma_kernel<false, false, 1><<<dim3(3, NCLS / 128), 256, 0, stream>>>(
        bufB, 384, wt + WT_CM2, cm_b2, 160, CD, 192, 384,
        lit_var, lit_sign, lp, ln, cmean, 1.f / 1024.f, 10);

    // clause_state pair_norm update
    pairnorm_update_kernel<<<NCLS / 4, 256, 0, stream>>>(CD, 192, 32, cmean, cst, xcmb, 192, 1024);

    // ug input tail
    xug_tail_kernel<<<NVARS * 128 / 256, 256, 0, stream>>>(vg, lp, ln, xugb);

    // ug MLP
    gemm_mfma_kernel<true, true, 0><<<dim3(4, NVARS / 128), 256, 0, stream>>>(
        xugb, 256, wt + WT_UG0, ug_b0, 256, bufA, 256, 256,
        nullptr, nullptr, nullptr, nullptr, nullptr, 0.f, 0);
    gemm_mfma_kernel<true, true, 0><<<dim3(4, NVARS / 128), 256, 0, stream>>>(
        bufA, 256, wt + WT_UG1, ug_b1, 256, bufB, 256, 256,
        nullptr, nullptr, nullptr, nullptr, nullptr, 0.f, 0);
    gemm_mfma_kernel<false, false, 2><<<dim3(2, NVARS / 128), 256, 0, stream>>>(
        bufB, 256, wt + WT_UG2, ug_b2, 128, CD, 128, 256,
        nullptr, nullptr, nullptr, nullptr, vmean, 1.f / 512.f, 9);

    // variables pair_norm update
    pairnorm_update_kernel<<<NVARS / 4, 256, 0, stream>>>(CD, 128, 0, vmean, var, xugb, 256, 512);

    // vo MLP -> logits
    fused_vo_kernel<<<NVARS / 64, 256, 0, stream>>>(
        xugb, wt + WT_VO0, wt + WT_VO1, vo_b0, vo_b1, vo_w2, vo_b2, logits);

    // loss
    fused_loss_kernel<<<NG, 1024, 0, stream>>>(logits, lit_var, lit_sign, loss);
  }

  finalize_kernel<<<1, 1, 0, stream>>>(loss, loss_out);
}

// Round 4
// 719.112 us; speedup vs baseline: 3.3818x; 1.0039x over previous
//
#include <hip/hip_runtime.h>
#include <hip/hip_bf16.h>
#include <math.h>

#define NG     32
#define NVARS  16384
#define NCLS   32768
#define NLITS  98304
#define NROUNDS 4

typedef __attribute__((ext_vector_type(8))) short bf16x8;
typedef __attribute__((ext_vector_type(4))) float f32x4;

// ---------------- workspace layout (float units) ----------------
#define OFF_VAR    ((size_t)0)            // f32 16384x128
#define OFF_CST    ((size_t)2097152)      // f32 32768x128
#define OFF_XCMB   ((size_t)6291456)      // bf16 32768x192
#define OFF_XUGB   ((size_t)9437184)      // bf16 16384x256
#define OFF_ABUF   ((size_t)11534336)     // bf16 32768x384
#define OFF_BBUF   ((size_t)17825792)     // bf16 32768x384
#define OFF_CD     ((size_t)24117248)     // f32 32768x192 (also UO 16384x128)
#define OFF_Q      ((size_t)30408704)     // f32 16384x32
// zero block (zeroed per round inside fused_vq, contiguous):
#define OFF_VG     ((size_t)30932992)     // f32 16384x32
#define OFF_LP     ((size_t)31457280)     // f32 16384x32
#define OFF_LN     ((size_t)31981568)     // f32 16384x32
#define OFF_CMEAN  ((size_t)32505856)     // f32 32x128
#define OFF_VMEAN  ((size_t)32509952)     // f32 32x128
#define ZERO_FLOATS ((size_t)1581056)
#define OFF_LOSS   ((size_t)32514048)     // f32 1
#define OFF_WT     ((size_t)32514052)     // bf16 pool 507904 elems

// Wt sub-offsets (bf16 elements within WT pool)
#define WT_CM0  ((size_t)0)       // [384][192]
#define WT_CM1  ((size_t)73728)   // [384][384]
#define WT_CM2  ((size_t)221184)  // [192][384]
#define WT_UG0  ((size_t)294912)  // [256][256]
#define WT_UG1  ((size_t)360448)  // [256][256]
#define WT_UG2  ((size_t)425984)  // [128][256]
#define WT_VO0  ((size_t)458752)  // [128][128]
#define WT_VO1  ((size_t)475136)  // [128][128]
#define WT_VQ0  ((size_t)491520)  // [64][160]
#define WT_VQ1  ((size_t)501760)  // [64][64]
#define WT_VQ2  ((size_t)505856)  // [32][64]

__device__ __forceinline__ float softplus_f(float x) {
  return fmaxf(x, 0.f) + log1pf(expf(-fabsf(x)));
}
__device__ __forceinline__ short f2bf(float x) {
  __hip_bfloat16 h = __float2bfloat16(x);
  return *reinterpret_cast<short*>(&h);
}
__device__ __forceinline__ float bf2f(short s) {
  __hip_bfloat16 h = *reinterpret_cast<__hip_bfloat16*>(&s);
  return __bfloat162float(h);
}

// ---------------- init: states + constant pads + loss=0 ----------------
__global__ void init_state_kernel(float* __restrict__ var, float* __restrict__ cst,
                                  short* __restrict__ xugb, short* __restrict__ xcmb,
                                  float* __restrict__ loss) {
  int t = blockIdx.x * blockDim.x + threadIdx.x;
  if (t == 0) *loss = 0.f;
  const int main_total = (NVARS + NCLS) * 128;
  if (t < main_total) {
    int row = t >> 7, m = t & 127;
    const float base = 2.82842712474619f; // sqrt(128)*0.25
    float val = ((m == 0) ? (1.f - 1.f / 128.f) : (-1.f / 128.f)) * base;
    if (row < NVARS) {
      var[(size_t)row * 128 + m] = val;
      xugb[(size_t)row * 256 + m] = f2bf(val);
    } else {
      int c = row - NVARS;
      cst[(size_t)c * 128 + m] = val;
      xcmb[(size_t)c * 192 + m] = f2bf(val);
    }
    return;
  }
  int t2 = t - main_total;
  if (t2 < NVARS * 32) {           // xugb cols 224..255 = 0 (forever)
    int row = t2 >> 5, j = t2 & 31;
    xugb[(size_t)row * 256 + 224 + j] = 0;
    return;
  }
  int t3 = t2 - NVARS * 32;
  if (t3 < NCLS * 32) {            // xcmb cols 160..191 = 0 (forever)
    int row = t3 >> 5, j = t3 & 31;
    xcmb[(size_t)row * 192 + 160 + j] = 0;
  }
}

// ---------------- one-shot weight convert+transpose+pad ----------------
__global__ void convert_all_kernel(
    const float* __restrict__ cm_w0, const float* __restrict__ cm_w1, const float* __restrict__ cm_w2,
    const float* __restrict__ ug_w0, const float* __restrict__ ug_w1, const float* __restrict__ ug_w2,
    const float* __restrict__ vo_w0, const float* __restrict__ vo_w1,
    const float* __restrict__ vq_w0, const float* __restrict__ vq_w1, const float* __restrict__ vq_w2,
    short* __restrict__ wt) {
  int t = blockIdx.x * blockDim.x + threadIdx.x;
  const float* W; int K, N, Kp; size_t base; int idx;
  if      (t < 73728)  { W = cm_w0; K = 160; N = 384; Kp = 192; base = WT_CM0; idx = t; }
  else if (t < 221184) { W = cm_w1; K = 384; N = 384; Kp = 384; base = WT_CM1; idx = t - 73728; }
  else if (t < 294912) { W = cm_w2; K = 384; N = 160; Kp = 384; base = WT_CM2; idx = t - 221184; }
  else if (t < 360448) { W = ug_w0; K = 224; N = 256; Kp = 256; base = WT_UG0; idx = t - 294912; }
  else if (t < 425984) { W = ug_w1; K = 256; N = 256; Kp = 256; base = WT_UG1; idx = t - 360448; }
  else if (t < 458752) { W = ug_w2; K = 256; N = 128; Kp = 256; base = WT_UG2; idx = t - 425984; }
  else if (t < 475136) { W = vo_w0; K = 128; N = 128; Kp = 128; base = WT_VO0; idx = t - 458752; }
  else if (t < 491520) { W = vo_w1; K = 128; N = 128; Kp = 128; base = WT_VO1; idx = t - 475136; }
  else if (t < 501760) { W = vq_w0; K = 132; N = 64;  Kp = 160; base = WT_VQ0; idx = t - 491520; }
  else if (t < 505856) { W = vq_w1; K = 64;  N = 64;  Kp = 64;  base = WT_VQ1; idx = t - 501760; }
  else if (t < 507904) { W = vq_w2; K = 64;  N = 32;  Kp = 64;  base = WT_VQ2; idx = t - 505856; }
  else return;
  int n = idx / Kp, k = idx - n * Kp;
  float v = (k < K && n < N) ? W[(size_t)k * N + n] : 0.f;
  wt[base + idx] = f2bf(v);
}

// ---------------- fused vq MLP: xugb[:, :128] (+noise) -> Q f32 ----------------
// Also zeroes the per-round accumulator block (vg/lp/ln/cmean/vmean).
__global__ __launch_bounds__(256) void fused_vq_kernel(
    const short* __restrict__ xugb, const float* __restrict__ noise,
    const short* __restrict__ w0, const short* __restrict__ w1, const short* __restrict__ w2,
    const float* __restrict__ b0, const float* __restrict__ b1, const float* __restrict__ b2,
    float* __restrict__ Q, float* __restrict__ zerobase) {
  // fold: zero the accumulator block (consumed by later kernels this round)
  {
    unsigned gid = blockIdx.x * 256 + threadIdx.x;
    float4 z4 = make_float4(0.f, 0.f, 0.f, 0.f);
    for (size_t i = gid; i < ZERO_FLOATS / 4; i += (size_t)(NVARS / 64) * 256)
      ((float4*)zerobase)[i] = z4;
  }
  __shared__ short A[64 * 160];
  __shared__ short H1[4][16 * 64];
  __shared__ short H2[4][16 * 64];
  const int wid = threadIdx.x >> 6, lane = threadIdx.x & 63;
  const int rbase = blockIdx.x * 64 + wid * 16;
  #pragma unroll
  for (int i = 0; i < 4; ++i) {
    int s = i * 64 + lane;
    int row = s >> 4, c8 = s & 15;
    *(bf16x8*)&A[(wid * 16 + row) * 160 + c8 * 8] =
        *(const bf16x8*)&xugb[(size_t)(rbase + row) * 256 + c8 * 8];
  }
  {
    int row = lane >> 2, seg = lane & 3;
    bf16x8 z = {0, 0, 0, 0, 0, 0, 0, 0};
    if (seg == 0) {
      float4 nz = *(const float4*)&noise[(size_t)(rbase + row) * 4];
      z[0] = f2bf(nz.x); z[1] = f2bf(nz.y); z[2] = f2bf(nz.z); z[3] = f2bf(nz.w);
    }
    *(bf16x8*)&A[(wid * 16 + row) * 160 + 128 + seg * 8] = z;
  }
  const int kof = (lane >> 4) * 8;
  const int l15 = lane & 15;
  // layer0: K=160, N=64
  f32x4 acc[4] = {};
  #pragma unroll
  for (int ks = 0; ks < 5; ++ks) {
    bf16x8 a = *(const bf16x8*)&A[(wid * 16 + l15) * 160 + ks * 32 + kof];
    #pragma unroll
    for (int ni = 0; ni < 4; ++ni) {
      bf16x8 b = *(const bf16x8*)&w0[(ni * 16 + l15) * 160 + ks * 32 + kof];
      acc[ni] = __builtin_amdgcn_mfma_f32_16x16x32_bf16(a, b, acc[ni], 0, 0, 0);
    }
  }
  #pragma unroll
  for (int ni = 0; ni < 4; ++ni) {
    int col = ni * 16 + l15;
    float bb = b0[col];
    #pragma unroll
    for (int j = 0; j < 4; ++j) {
      float v = acc[ni][j] + bb; v = v > 0.f ? v : 0.2f * v;
      H1[wid][((lane >> 4) * 4 + j) * 64 + col] = f2bf(v);
    }
  }
  // layer1: K=64, N=64
  f32x4 acc2[4] = {};
  #pragma unroll
  for (int ks = 0; ks < 2; ++ks) {
    bf16x8 a = *(const bf16x8*)&H1[wid][l15 * 64 + ks * 32 + kof];
    #pragma unroll
    for (int ni = 0; ni < 4; ++ni) {
      bf16x8 b = *(const bf16x8*)&w1[(ni * 16 + l15) * 64 + ks * 32 + kof];
      acc2[ni] = __builtin_amdgcn_mfma_f32_16x16x32_bf16(a, b, acc2[ni], 0, 0, 0);
    }
  }
  #pragma unroll
  for (int ni = 0; ni < 4; ++ni) {
    int col = ni * 16 + l15;
    float bb = b1[col];
    #pragma unroll
    for (int j = 0; j < 4; ++j) {
      float v = acc2[ni][j] + bb; v = v > 0.f ? v : 0.2f * v;
      H2[wid][((lane >> 4) * 4 + j) * 64 + col] = f2bf(v);
    }
  }
  // layer2: K=64, N=32
  f32x4 acc3[2] = {};
  #pragma unroll
  for (int ks = 0; ks < 2; ++ks) {
    bf16x8 a = *(const bf16x8*)&H2[wid][l15 * 64 + ks * 32 + kof];
    #pragma unroll
    for (int ni = 0; ni < 2; ++ni) {
      bf16x8 b = *(const bf16x8*)&w2[(ni * 16 + l15) * 64 + ks * 32 + kof];
      acc3[ni] = __builtin_amdgcn_mfma_f32_16x16x32_bf16(a, b, acc3[ni], 0, 0, 0);
    }
  }
  #pragma unroll
  for (int ni = 0; ni < 2; ++ni) {
    int col = ni * 16 + l15;
    float bb = b2[col];
    #pragma unroll
    for (int j = 0; j < 4; ++j)
      Q[(size_t)(rbase + (lane >> 4) * 4 + j) * 32 + col] = acc3[ni][j] + bb;
  }
}

// ---------------- fused clause_val + bf16 tail + grad scatter ----------------
__global__ void fused_clause_kernel(const float* __restrict__ Q, const int* __restrict__ lit_var,
                                    const int* __restrict__ lit_sign,
                                    short* __restrict__ xcmb, float* __restrict__ vg) {
  int t = blockIdx.x * blockDim.x + threadIdx.x;
  if (t >= NCLS * 32) return;
  int c = t >> 5, m = t & 31;
  int l0 = 3 * c;
  int v0 = lit_var[l0], v1 = lit_var[l0 + 1], v2 = lit_var[l0 + 2];
  int s0 = lit_sign[l0], s1 = lit_sign[l0 + 1], s2 = lit_sign[l0 + 2];
  float q0 = Q[(size_t)v0 * 32 + m];
  float q1 = Q[(size_t)v1 * 32 + m];
  float q2 = Q[(size_t)v2 * 32 + m];
  float sp = softplus_f(q0 * (float)s0) + softplus_f(q1 * (float)s1) + softplus_f(q2 * (float)s2);
  float cl = expf(-sp);
  xcmb[(size_t)c * 192 + 128 + m] = f2bf(cl);
  float g0 = 1.f / (1.f + expf(-q0)) - (s0 < 0 ? 1.f : 0.f);
  float g1 = 1.f / (1.f + expf(-q1)) - (s1 < 0 ? 1.f : 0.f);
  float g2 = 1.f / (1.f + expf(-q2)) - (s2 < 0 ? 1.f : 0.f);
  atomicAdd(&vg[(size_t)v0 * 32 + m], -cl * g0);
  atomicAdd(&vg[(size_t)v1 * 32 + m], -cl * g1);
  atomicAdd(&vg[(size_t)v2 * 32 + m], -cl * g2);
}

// ---------------- bf16 MFMA GEMM, tile 128 x TN, fused epilogues ----------------
// TN in {64,128}. Waves 2x2; per-wave quadrant 64 x TN/2.
// EPI 0: plain (RELU/OUTBF16). EPI 1: cm2 (f32 out cols 32..159, vloss scatter, cmean).
// EPI 2: ug2 (f32 out all cols, vmean).
template<int TN, bool RELU, bool OUTBF16, int EPI>
__global__ __launch_bounds__(256) void gemm_mfma_kernel(
    const short* __restrict__ A, int lda,
    const short* __restrict__ Wt,
    const float* __restrict__ bias, int nbias,
    void* __restrict__ Cout, int Np, int Kp,
    const int* __restrict__ lit_var, const int* __restrict__ lit_sign,
    float* __restrict__ lp, float* __restrict__ ln,
    float* __restrict__ meanbuf, float inv_cnt, int gshift) {
  constexpr int NB = TN / 32;        // N-fragments per wave (2 or 4)
  __shared__ short As[128 * 64];
  __shared__ short Bs[TN * 64];
  const int bn = blockIdx.x * TN;
  const int bm = blockIdx.y * 128;
  const int tid  = threadIdx.x;
  const int wid  = tid >> 6;
  const int lane = tid & 63;
  const int wm = (wid >> 1) * 64;
  const int wn = (wid & 1) * (TN / 2);

  f32x4 acc[4][NB] = {};

  for (int k0 = 0; k0 < Kp; k0 += 64) {
    #pragma unroll
    for (int i = 0; i < 4; ++i) {
      int s = (i * 4 + wid) * 64 + lane;
      int row = s >> 3, cs = (s & 7) << 3;
      const short* src = A + (size_t)(bm + row) * lda + k0 + cs;
      __builtin_amdgcn_global_load_lds(
          (const __attribute__((address_space(1))) void*)src,
          (__attribute__((address_space(3))) void*)(As + (size_t)(i * 4 + wid) * 64 * 8),
          16, 0, 0);
    }
    #pragma unroll
    for (int i = 0; i < TN / 32; ++i) {
      int s = (i * 4 + wid) * 64 + lane;
      int n = s >> 3, cs = (s & 7) << 3;
      const short* src = Wt + (size_t)(bn + n) * Kp + k0 + cs;
      __builtin_amdgcn_global_load_lds(
          (const __attribute__((address_space(1))) void*)src,
          (__attribute__((address_space(3))) void*)(Bs + (size_t)(i * 4 + wid) * 64 * 8),
          16, 0, 0);
    }
    __syncthreads();

    #pragma unroll
    for (int ks = 0; ks < 2; ++ks) {
      const int kof = ks * 32 + (lane >> 4) * 8;
      bf16x8 a[4], b[NB];
      #pragma unroll
      for (int mi = 0; mi < 4; ++mi)
        a[mi] = *(const bf16x8*)&As[(wm + mi * 16 + (lane & 15)) * 64 + kof];
      #pragma unroll
      for (int ni = 0; ni < NB; ++ni)
        b[ni] = *(const bf16x8*)&Bs[(wn + ni * 16 + (lane & 15)) * 64 + kof];
      #pragma unroll
      for (int mi = 0; mi < 4; ++mi)
        #pragma unroll
        for (int ni = 0; ni < NB; ++ni)
          acc[mi][ni] = __builtin_amdgcn_mfma_f32_16x16x32_bf16(a[mi], b[ni], acc[mi][ni], 0, 0, 0);
    }
    __syncthreads();
  }

  const int col0 = bn + wn + (lane & 15);
  const int row0 = bm + wm + (lane >> 4) * 4;
  #pragma unroll
  for (int ni = 0; ni < NB; ++ni) {
    int col = col0 + ni * 16;
    float bv = (col < nbias) ? bias[col] : 0.f;
    float colsum = 0.f;
    #pragma unroll
    for (int mi = 0; mi < 4; ++mi) {
      #pragma unroll
      for (int j = 0; j < 4; ++j) {
        int row = row0 + mi * 16 + j;
        float v = acc[mi][ni][j] + bv;
        if (EPI == 0) {
          if (RELU) v = v > 0.f ? v : 0.2f * v;
          if (OUTBF16) ((short*)Cout)[(size_t)row * Np + col] = f2bf(v);
          else         ((float*)Cout)[(size_t)row * Np + col] = v;
        } else if (EPI == 1) {
          if (col < 32) {
            #pragma unroll
            for (int i = 0; i < 3; ++i) {
              int l = 3 * row + i;
              int vv = lit_var[l];
              float* tgt = (lit_sign[l] > 0) ? lp : ln;
              atomicAdd(&tgt[(size_t)vv * 32 + col], v);
            }
          } else if (col < 160) {
            ((float*)Cout)[(size_t)row * Np + col] = v;
            colsum += v;
          }
        } else { // EPI == 2
          ((float*)Cout)[(size_t)row * Np + col] = v;
          colsum += v;
        }
      }
    }
    if ((EPI == 1 && col >= 32 && col < 160) || EPI == 2) {
      colsum += __shfl_xor(colsum, 16);
      colsum += __shfl_xor(colsum, 32);
      if ((lane >> 4) == 0) {
        int midx = (EPI == 1) ? (col - 32) : col;
        atomicAdd(&meanbuf[(size_t)(bm >> gshift) * 128 + midx], colsum * inv_cnt);
      }
    }
  }
}

// ---------------- pair_norm + state update + bf16 copy ----------------
__global__ __launch_bounds__(256) void pairnorm_update_kernel(
    const float* __restrict__ x, int stride, int coloff,
    const float* __restrict__ mean, float* __restrict__ state,
    short* __restrict__ bout, int bstride, int rows_per_g) {
  int wid = threadIdx.x >> 6;
  int lane = threadIdx.x & 63;
  int row = blockIdx.x * 4 + wid;
  int g = row / rows_per_g;
  const float* xp = x + (size_t)row * stride + coloff;
  float y0 = xp[lane]      - mean[g * 128 + lane];
  float y1 = xp[lane + 64] - mean[g * 128 + lane + 64];
  float ss = y0 * y0 + y1 * y1;
  #pragma unroll
  for (int o = 32; o > 0; o >>= 1) ss += __shfl_xor(ss, o);
  float inv = rsqrtf(ss * (1.f / 128.f) + 1e-6f);
  float* sp = state + (size_t)row * 128;
  float s0 = y0 * inv * 0.25f + 0.1f * sp[lane];
  float s1 = y1 * inv * 0.25f + 0.1f * sp[lane + 64];
  sp[lane]      = s0;
  sp[lane + 64] = s1;
  bout[(size_t)row * bstride + lane]      = f2bf(s0);
  bout[(size_t)row * bstride + lane + 64] = f2bf(s1);
}

// ---------------- vg/lp/ln -> xugb bf16 cols 128..223 ----------------
__global__ void xug_tail_kernel(const float* __restrict__ vg, const float* __restrict__ lp,
                                const float* __restrict__ ln, short* __restrict__ xugb) {
  int t = blockIdx.x * blockDim.x + threadIdx.x;
  if (t >= NVARS * 128) return;
  int v = t >> 7, j = t & 127;
  if (j >= 96) return;  // cols 224..255 init-zeroed
  float x;
  if (j < 32)       x = vg[(size_t)v * 32 + j];
  else if (j < 64)  x = lp[(size_t)v * 32 + (j - 32)];
  else              x = ln[(size_t)v * 32 + (j - 64)];
  xugb[(size_t)v * 256 + 128 + j] = f2bf(x);
}

// ---------------- fused vo MLP: xugb[:, :128] -> logits f32 ----------------
__global__ __launch_bounds__(256) void fused_vo_kernel(
    const short* __restrict__ xugb,
    const short* __restrict__ w0, const short* __restrict__ w1,
    const float* __restrict__ b0, const float* __restrict__ b1,
    const float* __restrict__ w2, const float* __restrict__ b2,
    float* __restrict__ logits) {
  __shared__ short A[64 * 128];
  __shared__ short H1[4][16 * 128];
  __shared__ short H2[4][16 * 128];
  const int wid = threadIdx.x >> 6, lane = threadIdx.x & 63;
  const int rbase = blockIdx.x * 64 + wid * 16;
  #pragma unroll
  for (int i = 0; i < 4; ++i) {
    int s = i * 64 + lane;
    int row = s >> 4, c8 = s & 15;
    *(bf16x8*)&A[(wid * 16 + row) * 128 + c8 * 8] =
        *(const bf16x8*)&xugb[(size_t)(rbase + row) * 256 + c8 * 8];
  }
  const int kof = (lane >> 4) * 8;
  const int l15 = lane & 15;
  f32x4 acc[8] = {};
  #pragma unroll
  for (int ks = 0; ks < 4; ++ks) {
    bf16x8 a = *(const bf16x8*)&A[(wid * 16 + l15) * 128 + ks * 32 + kof];
    #pragma unroll
    for (int ni = 0; ni < 8; ++ni) {
      bf16x8 b = *(const bf16x8*)&w0[(ni * 16 + l15) * 128 + ks * 32 + kof];
      acc[ni] = __builtin_amdgcn_mfma_f32_16x16x32_bf16(a, b, acc[ni], 0, 0, 0);
    }
  }
  #pragma unroll
  for (int ni = 0; ni < 8; ++ni) {
    int col = ni * 16 + l15;
    float bb = b0[col];
    #pragma unroll
    for (int j = 0; j < 4; ++j) {
      float v = acc[ni][j] + bb; v = v > 0.f ? v : 0.2f * v;
      H1[wid][((lane >> 4) * 4 + j) * 128 + col] = f2bf(v);
    }
  }
  f32x4 acc2[8] = {};
  #pragma unroll
  for (int ks = 0; ks < 4; ++ks) {
    bf16x8 a = *(const bf16x8*)&H1[wid][l15 * 128 + ks * 32 + kof];
    #pragma unroll
    for (int ni = 0; ni < 8; ++ni) {
      bf16x8 b = *(const bf16x8*)&w1[(ni * 16 + l15) * 128 + ks * 32 + kof];
      acc2[ni] = __builtin_amdgcn_mfma_f32_16x16x32_bf16(a, b, acc2[ni], 0, 0, 0);
    }
  }
  #pragma unroll
  for (int ni = 0; ni < 8; ++ni) {
    int col = ni * 16 + l15;
    float bb = b1[col];
    #pragma unroll
    for (int j = 0; j < 4; ++j) {
      float v = acc2[ni][j] + bb; v = v > 0.f ? v : 0.2f * v;
      H2[wid][((lane >> 4) * 4 + j) * 128 + col] = f2bf(v);
    }
  }
  {
    int row = lane >> 2, q = lane & 3;
    float s = 0.f;
    #pragma unroll
    for (int jj = 0; jj < 4; ++jj) {
      bf16x8 h = *(const bf16x8*)&H2[wid][row * 128 + q * 32 + jj * 8];
      #pragma unroll
      for (int e = 0; e < 8; ++e) s += bf2f(h[e]) * w2[q * 32 + jj * 8 + e];
    }
    s += __shfl_xor(s, 1);
    s += __shfl_xor(s, 2);
    if (q == 0) logits[rbase + row] = s + b2[0];
  }
}

// ---------------- fused per-clause loss + per-graph sqrt reduce ----------------
__global__ __launch_bounds__(1024) void fused_loss_kernel(
    const float* __restrict__ logits, const int* __restrict__ lit_var,
    const int* __restrict__ lit_sign, float* __restrict__ loss) {
  __shared__ float lg[512];
  __shared__ float red[16];
  int g = blockIdx.x, tid = threadIdx.x;
  if (tid < 512) lg[tid] = logits[(size_t)g * 512 + tid];
  __syncthreads();
  int c = g * 1024 + tid;
  float s = 0.f;
  #pragma unroll
  for (int i = 0; i < 3; ++i) {
    int l = 3 * c + i;
    float sg = (float)lit_sign[l];
    s += softplus_f(lg[lit_var[l] - g * 512] * sg);
  }
  float vv = expf(-s);
  float pcv = vv * (-logf(1.f - vv + 1e-8f));
  #pragma unroll
  for (int o = 32; o > 0; o >>= 1) pcv += __shfl_xor(pcv, o);
  if ((tid & 63) == 0) red[tid >> 6] = pcv;
  __syncthreads();
  if (tid < 16) {
    float x = red[tid];
    #pragma unroll
    for (int o = 8; o > 0; o >>= 1) x += __shfl_xor(x, o);
    if (tid == 0) atomicAdd(loss, sqrtf(x + 1e-6f));
  }
}

__global__ void finalize_kernel(const float* __restrict__ loss_acc, float* __restrict__ out) {
  out[0] = loss_acc[0] * 0.25f;
}

// =======================================================================
extern "C" void kernel_launch(void* const* d_in, const int* in_sizes, int n_in,
                              void* d_out, int out_size, void* d_ws, size_t ws_size,
                              hipStream_t stream) {
  const int* lit_var    = (const int*)d_in[0];
  const int* lit_sign   = (const int*)d_in[1];
  const float* noise    = (const float*)d_in[5];
  const float* vq_w0 = (const float*)d_in[6];   const float* vq_b0 = (const float*)d_in[7];
  const float* vq_w1 = (const float*)d_in[8];   const float* vq_b1 = (const float*)d_in[9];
  const float* vq_w2 = (const float*)d_in[10];  const float* vq_b2 = (const float*)d_in[11];
  const float* cm_w0 = (const float*)d_in[12];  const float* cm_b0 = (const float*)d_in[13];
  const float* cm_w1 = (const float*)d_in[14];  const float* cm_b1 = (const float*)d_in[15];
  const float* cm_w2 = (const float*)d_in[16];  const float* cm_b2 = (const float*)d_in[17];
  const float* ug_w0 = (const float*)d_in[18];  const float* ug_b0 = (const float*)d_in[19];
  const float* ug_w1 = (const float*)d_in[20];  const float* ug_b1 = (const float*)d_in[21];
  const float* ug_w2 = (const float*)d_in[22];  const float* ug_b2 = (const float*)d_in[23];
  const float* vo_w0 = (const float*)d_in[24];  const float* vo_b0 = (const float*)d_in[25];
  const float* vo_w1 = (const float*)d_in[26];  const float* vo_b1 = (const float*)d_in[27];
  const float* vo_w2 = (const float*)d_in[28];  const float* vo_b2 = (const float*)d_in[29];

  float* ws = (float*)d_ws;
  float* var   = ws + OFF_VAR;
  float* cst   = ws + OFF_CST;
  short* xcmb  = (short*)(ws + OFF_XCMB);
  short* xugb  = (short*)(ws + OFF_XUGB);
  short* bufA  = (short*)(ws + OFF_ABUF);
  short* bufB  = (short*)(ws + OFF_BBUF);
  float* CD    = ws + OFF_CD;
  float* Q     = ws + OFF_Q;
  float* vg    = ws + OFF_VG;
  float* lp    = ws + OFF_LP;
  float* ln    = ws + OFF_LN;
  float* cmean = ws + OFF_CMEAN;
  float* vmean = ws + OFF_VMEAN;
  float* loss  = ws + OFF_LOSS;
  short* wt    = (short*)(ws + OFF_WT);
  float* logits = (float*)d_out;
  float* loss_out = (float*)d_out + NVARS;

  convert_all_kernel<<<1984, 256, 0, stream>>>(cm_w0, cm_w1, cm_w2, ug_w0, ug_w1, ug_w2,
                                               vo_w0, vo_w1, vq_w0, vq_w1, vq_w2, wt);
  init_state_kernel<<<30720, 256, 0, stream>>>(var, cst, xugb, xcmb, loss);

  for (int r = 0; r < NROUNDS; ++r) {
    const float* noise_r = noise + (size_t)r * NVARS * 4;

    // vq MLP -> Q (also zeroes vg/lp/ln/cmean/vmean)
    fused_vq_kernel<<<NVARS / 64, 256, 0, stream>>>(
        xugb, noise_r, wt + WT_VQ0, wt + WT_VQ1, wt + WT_VQ2, vq_b0, vq_b1, vq_b2, Q, vg);

    // clause_val + xcmb tail + grad scatter
    fused_clause_kernel<<<NCLS * 32 / 256, 256, 0, stream>>>(Q, lit_var, lit_sign, xcmb, vg);

    // cm MLP
    gemm_mfma_kernel<128, true, true, 0><<<dim3(3, NCLS / 128), 256, 0, stream>>>(
        xcmb, 192, wt + WT_CM0, cm_b0, 384, bufA, 384, 192,
        nullptr, nullptr, nullptr, nullptr, nullptr, 0.f, 0);
    gemm_mfma_kernel<128, true, true, 0><<<dim3(3, NCLS / 128), 256, 0, stream>>>(
        bufA, 384, wt + WT_CM1, cm_b1, 384, bufB, 384, 384,
        nullptr, nullptr, nullptr, nullptr, nullptr, 0.f, 0);
    gemm_mfma_kernel<64, false, false, 1><<<dim3(3, NCLS / 128), 256, 0, stream>>>(
        bufB, 384, wt + WT_CM2, cm_b2, 160, CD, 192, 384,
        lit_var, lit_sign, lp, ln, cmean, 1.f / 1024.f, 10);

    // clause_state pair_norm update
    pairnorm_update_kernel<<<NCLS / 4, 256, 0, stream>>>(CD, 192, 32, cmean, cst, xcmb, 192, 1024);

    // ug input tail
    xug_tail_kernel<<<NVARS * 128 / 256, 256, 0, stream>>>(vg, lp, ln, xugb);

    // ug MLP
    gemm_mfma_kernel<128, true, true, 0><<<dim3(2, NVARS / 128), 256, 0, stream>>>(
        xugb, 256, wt + WT_UG0, ug_b0, 256, bufA, 256, 256,
        nullptr, nullptr, nullptr, nullptr, nullptr, 0.f, 0);
    gemm_mfma_kernel<128, true, true, 0><<<dim3(2, NVARS / 128), 256, 0, stream>>>(
        bufA, 256, wt + WT_UG1, ug_b1, 256, bufB, 256, 256,
        nullptr, nullptr, nullptr, nullptr, nullptr, 0.f, 0);
    gemm_mfma_kernel<64, false, false, 2><<<dim3(2, NVARS / 128), 256, 0, stream>>>(
        bufB, 256, wt + WT_UG2, ug_b2, 128, CD, 128, 256,
        nullptr, nullptr, nullptr, nullptr, vmean, 1.f / 512.f, 9);

    // variables pair_norm update
    pairnorm_update_kernel<<<NVARS / 4, 256, 0, stream>>>(CD, 128, 0, vmean, var, xugb, 256, 512);

    // vo MLP -> logits
    fused_vo_kernel<<<NVARS / 64, 256, 0, stream>>>(
        xugb, wt + WT_VO0, wt + WT_VO1, vo_b0, vo_b1, vo_w2, vo_b2, logits);

    // loss
    fused_loss_kernel<<<NG, 1024, 0, stream>>>(logits, lit_var, lit_sign, loss);
  }

  finalize_kernel<<<1, 1, 0, stream>>>(loss, loss_out);
}

// Round 5
// 682.138 us; speedup vs baseline: 3.5651x; 1.0542x over previous
//
#include <hip/hip_runtime.h>
#include <hip/hip_bf16.h>
#include <math.h>

#define NG     32
#define NVARS  16384
#define NCLS   32768
#define NLITS  98304
#define NROUNDS 4

typedef __attribute__((ext_vector_type(8))) short bf16x8;
typedef __attribute__((ext_vector_type(4))) float f32x4;

// ---------------- workspace layout (float units) ----------------
#define OFF_VAR    ((size_t)0)            // f32 16384x128
#define OFF_CST    ((size_t)2097152)      // f32 32768x128
#define OFF_XCMB   ((size_t)6291456)      // bf16 32768x192
#define OFF_XUGB   ((size_t)9437184)      // bf16 16384x256
#define OFF_ABUF   ((size_t)11534336)     // bf16 32768x384
#define OFF_BBUF   ((size_t)17825792)     // bf16 32768x384
#define OFF_CD     ((size_t)24117248)     // f32 32768x192
#define OFF_Q      ((size_t)30408704)     // f32 16384x32
#define OFF_CLF    ((size_t)30932992)     // f32 32768x32
#define OFF_VLOSS  ((size_t)31981568)     // f32 32768x32
#define OFF_CMEAN  ((size_t)33030144)     // f32 32x128  (cmean+vmean contiguous, zeroed together)
#define OFF_VMEAN  ((size_t)33034240)     // f32 32x128
#define OFF_LOSS   ((size_t)33038336)     // f32 1
#define OFF_CSO    ((size_t)33038340)     // int 16385 (csr offsets)
#define OFF_CSE    ((size_t)33054725)     // int 98304 (csr entries: (clause<<1)|pos)
#define OFF_CSC    ((size_t)33153029)     // int 16384 (counts / cursors)
#define OFF_WT     ((size_t)33169416)     // bf16 pool 507904 elems (16B aligned)

// Wt sub-offsets (bf16 elements within WT pool)
#define WT_CM0  ((size_t)0)       // [384][192]
#define WT_CM1  ((size_t)73728)   // [384][384]
#define WT_CM2  ((size_t)221184)  // [192][384]
#define WT_UG0  ((size_t)294912)  // [256][256]
#define WT_UG1  ((size_t)360448)  // [256][256]
#define WT_UG2  ((size_t)425984)  // [128][256]
#define WT_VO0  ((size_t)458752)  // [128][128]
#define WT_VO1  ((size_t)475136)  // [128][128]
#define WT_VQ0  ((size_t)491520)  // [64][160]
#define WT_VQ1  ((size_t)501760)  // [64][64]
#define WT_VQ2  ((size_t)505856)  // [32][64]

__device__ __forceinline__ float softplus_f(float x) {
  return fmaxf(x, 0.f) + log1pf(expf(-fabsf(x)));
}
__device__ __forceinline__ short f2bf(float x) {
  __hip_bfloat16 h = __float2bfloat16(x);
  return *reinterpret_cast<short*>(&h);
}
__device__ __forceinline__ float bf2f(short s) {
  __hip_bfloat16 h = *reinterpret_cast<__hip_bfloat16*>(&s);
  return __bfloat162float(h);
}

// ---------------- init: states + constant pads + loss=0 + csr-count zero ----------------
__global__ void init_state_kernel(float* __restrict__ var, float* __restrict__ cst,
                                  short* __restrict__ xugb, short* __restrict__ xcmb,
                                  float* __restrict__ loss, int* __restrict__ cnt) {
  int t = blockIdx.x * blockDim.x + threadIdx.x;
  if (t == 0) *loss = 0.f;
  const int main_total = (NVARS + NCLS) * 128;
  if (t < main_total) {
    int row = t >> 7, m = t & 127;
    const float base = 2.82842712474619f; // sqrt(128)*0.25
    float val = ((m == 0) ? (1.f - 1.f / 128.f) : (-1.f / 128.f)) * base;
    if (row < NVARS) {
      var[(size_t)row * 128 + m] = val;
      xugb[(size_t)row * 256 + m] = f2bf(val);
    } else {
      int c = row - NVARS;
      cst[(size_t)c * 128 + m] = val;
      xcmb[(size_t)c * 192 + m] = f2bf(val);
    }
    return;
  }
  int t2 = t - main_total;
  if (t2 < NVARS * 32) {           // xugb cols 224..255 = 0 (forever)
    int row = t2 >> 5, j = t2 & 31;
    xugb[(size_t)row * 256 + 224 + j] = 0;
    return;
  }
  int t3 = t2 - NVARS * 32;
  if (t3 < NCLS * 32) {            // xcmb cols 160..191 = 0 (forever)
    int row = t3 >> 5, j = t3 & 31;
    xcmb[(size_t)row * 192 + 160 + j] = 0;
    return;
  }
  int t4 = t3 - NCLS * 32;
  if (t4 < NVARS) cnt[t4] = 0;     // CSR counts
}

// ---------------- CSR build: count, scan, fill ----------------
__global__ void csr_count_kernel(const int* __restrict__ lit_var, int* __restrict__ cnt) {
  int l = blockIdx.x * blockDim.x + threadIdx.x;
  if (l >= NLITS) return;
  atomicAdd(&cnt[lit_var[l]], 1);
}

__global__ __launch_bounds__(1024) void csr_scan_kernel(const int* __restrict__ cnt,
                                                        int* __restrict__ cso,
                                                        int* __restrict__ cur) {
  __shared__ int part[1024];
  int t = threadIdx.x;
  int base = t * 16;
  int local[16];
  int s = 0;
  #pragma unroll
  for (int i = 0; i < 16; ++i) { local[i] = cnt[base + i]; s += local[i]; }
  part[t] = s;
  __syncthreads();
  for (int off = 1; off < 1024; off <<= 1) {
    int v = (t >= off) ? part[t - off] : 0;
    __syncthreads();
    part[t] += v;
    __syncthreads();
  }
  int run = part[t] - s;   // exclusive prefix
  #pragma unroll
  for (int i = 0; i < 16; ++i) {
    cso[base + i] = run;
    cur[base + i] = run;
    run += local[i];
  }
  if (t == 1023) cso[NVARS] = run;
}

__global__ void csr_fill_kernel(const int* __restrict__ lit_var, const int* __restrict__ lit_sign,
                                const int* __restrict__ lit_clause,
                                int* __restrict__ cur, int* __restrict__ cse) {
  int l = blockIdx.x * blockDim.x + threadIdx.x;
  if (l >= NLITS) return;
  int v = lit_var[l];
  int pos = atomicAdd(&cur[v], 1);
  cse[pos] = (lit_clause[l] << 1) | (lit_sign[l] > 0 ? 1 : 0);
}

// ---------------- one-shot weight convert+transpose+pad ----------------
__global__ void convert_all_kernel(
    const float* __restrict__ cm_w0, const float* __restrict__ cm_w1, const float* __restrict__ cm_w2,
    const float* __restrict__ ug_w0, const float* __restrict__ ug_w1, const float* __restrict__ ug_w2,
    const float* __restrict__ vo_w0, const float* __restrict__ vo_w1,
    const float* __restrict__ vq_w0, const float* __restrict__ vq_w1, const float* __restrict__ vq_w2,
    short* __restrict__ wt) {
  int t = blockIdx.x * blockDim.x + threadIdx.x;
  const float* W; int K, N, Kp; size_t base; int idx;
  if      (t < 73728)  { W = cm_w0; K = 160; N = 384; Kp = 192; base = WT_CM0; idx = t; }
  else if (t < 221184) { W = cm_w1; K = 384; N = 384; Kp = 384; base = WT_CM1; idx = t - 73728; }
  else if (t < 294912) { W = cm_w2; K = 384; N = 160; Kp = 384; base = WT_CM2; idx = t - 221184; }
  else if (t < 360448) { W = ug_w0; K = 224; N = 256; Kp = 256; base = WT_UG0; idx = t - 294912; }
  else if (t < 425984) { W = ug_w1; K = 256; N = 256; Kp = 256; base = WT_UG1; idx = t - 360448; }
  else if (t < 458752) { W = ug_w2; K = 256; N = 128; Kp = 256; base = WT_UG2; idx = t - 425984; }
  else if (t < 475136) { W = vo_w0; K = 128; N = 128; Kp = 128; base = WT_VO0; idx = t - 458752; }
  else if (t < 491520) { W = vo_w1; K = 128; N = 128; Kp = 128; base = WT_VO1; idx = t - 475136; }
  else if (t < 501760) { W = vq_w0; K = 132; N = 64;  Kp = 160; base = WT_VQ0; idx = t - 491520; }
  else if (t < 505856) { W = vq_w1; K = 64;  N = 64;  Kp = 64;  base = WT_VQ1; idx = t - 501760; }
  else if (t < 507904) { W = vq_w2; K = 64;  N = 32;  Kp = 64;  base = WT_VQ2; idx = t - 505856; }
  else return;
  int n = idx / Kp, k = idx - n * Kp;
  float v = (k < K && n < N) ? W[(size_t)k * N + n] : 0.f;
  wt[base + idx] = f2bf(v);
}

// ---------------- fused vq MLP: xugb[:, :128] (+noise) -> Q f32 ----------------
__global__ __launch_bounds__(256) void fused_vq_kernel(
    const short* __restrict__ xugb, const float* __restrict__ noise,
    const short* __restrict__ w0, const short* __restrict__ w1, const short* __restrict__ w2,
    const float* __restrict__ b0, const float* __restrict__ b1, const float* __restrict__ b2,
    float* __restrict__ Q) {
  __shared__ short A[64 * 160];
  __shared__ short H1[4][16 * 64];
  __shared__ short H2[4][16 * 64];
  const int wid = threadIdx.x >> 6, lane = threadIdx.x & 63;
  const int rbase = blockIdx.x * 64 + wid * 16;
  #pragma unroll
  for (int i = 0; i < 4; ++i) {
    int s = i * 64 + lane;
    int row = s >> 4, c8 = s & 15;
    *(bf16x8*)&A[(wid * 16 + row) * 160 + c8 * 8] =
        *(const bf16x8*)&xugb[(size_t)(rbase + row) * 256 + c8 * 8];
  }
  {
    int row = lane >> 2, seg = lane & 3;
    bf16x8 z = {0, 0, 0, 0, 0, 0, 0, 0};
    if (seg == 0) {
      float4 nz = *(const float4*)&noise[(size_t)(rbase + row) * 4];
      z[0] = f2bf(nz.x); z[1] = f2bf(nz.y); z[2] = f2bf(nz.z); z[3] = f2bf(nz.w);
    }
    *(bf16x8*)&A[(wid * 16 + row) * 160 + 128 + seg * 8] = z;
  }
  const int kof = (lane >> 4) * 8;
  const int l15 = lane & 15;
  // layer0: K=160, N=64
  f32x4 acc[4] = {};
  #pragma unroll
  for (int ks = 0; ks < 5; ++ks) {
    bf16x8 a = *(const bf16x8*)&A[(wid * 16 + l15) * 160 + ks * 32 + kof];
    #pragma unroll
    for (int ni = 0; ni < 4; ++ni) {
      bf16x8 b = *(const bf16x8*)&w0[(ni * 16 + l15) * 160 + ks * 32 + kof];
      acc[ni] = __builtin_amdgcn_mfma_f32_16x16x32_bf16(a, b, acc[ni], 0, 0, 0);
    }
  }
  #pragma unroll
  for (int ni = 0; ni < 4; ++ni) {
    int col = ni * 16 + l15;
    float bb = b0[col];
    #pragma unroll
    for (int j = 0; j < 4; ++j) {
      float v = acc[ni][j] + bb; v = v > 0.f ? v : 0.2f * v;
      H1[wid][((lane >> 4) * 4 + j) * 64 + col] = f2bf(v);
    }
  }
  // layer1: K=64, N=64
  f32x4 acc2[4] = {};
  #pragma unroll
  for (int ks = 0; ks < 2; ++ks) {
    bf16x8 a = *(const bf16x8*)&H1[wid][l15 * 64 + ks * 32 + kof];
    #pragma unroll
    for (int ni = 0; ni < 4; ++ni) {
      bf16x8 b = *(const bf16x8*)&w1[(ni * 16 + l15) * 64 + ks * 32 + kof];
      acc2[ni] = __builtin_amdgcn_mfma_f32_16x16x32_bf16(a, b, acc2[ni], 0, 0, 0);
    }
  }
  #pragma unroll
  for (int ni = 0; ni < 4; ++ni) {
    int col = ni * 16 + l15;
    float bb = b1[col];
    #pragma unroll
    for (int j = 0; j < 4; ++j) {
      float v = acc2[ni][j] + bb; v = v > 0.f ? v : 0.2f * v;
      H2[wid][((lane >> 4) * 4 + j) * 64 + col] = f2bf(v);
    }
  }
  // layer2: K=64, N=32
  f32x4 acc3[2] = {};
  #pragma unroll
  for (int ks = 0; ks < 2; ++ks) {
    bf16x8 a = *(const bf16x8*)&H2[wid][l15 * 64 + ks * 32 + kof];
    #pragma unroll
    for (int ni = 0; ni < 2; ++ni) {
      bf16x8 b = *(const bf16x8*)&w2[(ni * 16 + l15) * 64 + ks * 32 + kof];
      acc3[ni] = __builtin_amdgcn_mfma_f32_16x16x32_bf16(a, b, acc3[ni], 0, 0, 0);
    }
  }
  #pragma unroll
  for (int ni = 0; ni < 2; ++ni) {
    int col = ni * 16 + l15;
    float bb = b2[col];
    #pragma unroll
    for (int j = 0; j < 4; ++j)
      Q[(size_t)(rbase + (lane >> 4) * 4 + j) * 32 + col] = acc3[ni][j] + bb;
  }
}

// ---------------- clause_val: cl f32 + bf16 tail; zeroes cmean/vmean ----------------
__global__ void fused_clause_kernel(const float* __restrict__ Q, const int* __restrict__ lit_var,
                                    const int* __restrict__ lit_sign,
                                    short* __restrict__ xcmb, float* __restrict__ clf,
                                    float* __restrict__ meanz) {
  int t = blockIdx.x * blockDim.x + threadIdx.x;
  if (t < 2 * 32 * 128) meanz[t] = 0.f;     // cmean+vmean
  if (t >= NCLS * 32) return;
  int c = t >> 5, m = t & 31;
  int l0 = 3 * c;
  int v0 = lit_var[l0], v1 = lit_var[l0 + 1], v2 = lit_var[l0 + 2];
  int s0 = lit_sign[l0], s1 = lit_sign[l0 + 1], s2 = lit_sign[l0 + 2];
  float q0 = Q[(size_t)v0 * 32 + m];
  float q1 = Q[(size_t)v1 * 32 + m];
  float q2 = Q[(size_t)v2 * 32 + m];
  float sp = softplus_f(q0 * (float)s0) + softplus_f(q1 * (float)s1) + softplus_f(q2 * (float)s2);
  float cl = expf(-sp);
  clf[(size_t)c * 32 + m] = cl;
  xcmb[(size_t)c * 192 + 128 + m] = f2bf(cl);
}

// ---------------- bf16 MFMA GEMM, tile 128 x TN, fused epilogues ----------------
// EPI 0: plain (RELU/OUTBF16). EPI 1: cm2 (vloss f32 cols<32; CD f32 cols 32..159 + cmean).
// EPI 2: ug2 (f32 out all cols, vmean).
template<int TN, bool RELU, bool OUTBF16, int EPI>
__global__ __launch_bounds__(256) void gemm_mfma_kernel(
    const short* __restrict__ A, int lda,
    const short* __restrict__ Wt,
    const float* __restrict__ bias, int nbias,
    void* __restrict__ Cout, int Np, int Kp,
    float* __restrict__ aux,       // vloss for EPI1
    float* __restrict__ meanbuf, float inv_cnt, int gshift) {
  constexpr int NB = TN / 32;
  __shared__ short As[128 * 64];
  __shared__ short Bs[TN * 64];
  const int bn = blockIdx.x * TN;
  const int bm = blockIdx.y * 128;
  const int tid  = threadIdx.x;
  const int wid  = tid >> 6;
  const int lane = tid & 63;
  const int wm = (wid >> 1) * 64;
  const int wn = (wid & 1) * (TN / 2);

  f32x4 acc[4][NB] = {};

  for (int k0 = 0; k0 < Kp; k0 += 64) {
    #pragma unroll
    for (int i = 0; i < 4; ++i) {
      int s = (i * 4 + wid) * 64 + lane;
      int row = s >> 3, cs = (s & 7) << 3;
      const short* src = A + (size_t)(bm + row) * lda + k0 + cs;
      __builtin_amdgcn_global_load_lds(
          (const __attribute__((address_space(1))) void*)src,
          (__attribute__((address_space(3))) void*)(As + (size_t)(i * 4 + wid) * 64 * 8),
          16, 0, 0);
    }
    #pragma unroll
    for (int i = 0; i < TN / 32; ++i) {
      int s = (i * 4 + wid) * 64 + lane;
      int n = s >> 3, cs = (s & 7) << 3;
      const short* src = Wt + (size_t)(bn + n) * Kp + k0 + cs;
      __builtin_amdgcn_global_load_lds(
          (const __attribute__((address_space(1))) void*)src,
          (__attribute__((address_space(3))) void*)(Bs + (size_t)(i * 4 + wid) * 64 * 8),
          16, 0, 0);
    }
    __syncthreads();

    #pragma unroll
    for (int ks = 0; ks < 2; ++ks) {
      const int kof = ks * 32 + (lane >> 4) * 8;
      bf16x8 a[4], b[NB];
      #pragma unroll
      for (int mi = 0; mi < 4; ++mi)
        a[mi] = *(const bf16x8*)&As[(wm + mi * 16 + (lane & 15)) * 64 + kof];
      #pragma unroll
      for (int ni = 0; ni < NB; ++ni)
        b[ni] = *(const bf16x8*)&Bs[(wn + ni * 16 + (lane & 15)) * 64 + kof];
      #pragma unroll
      for (int mi = 0; mi < 4; ++mi)
        #pragma unroll
        for (int ni = 0; ni < NB; ++ni)
          acc[mi][ni] = __builtin_amdgcn_mfma_f32_16x16x32_bf16(a[mi], b[ni], acc[mi][ni], 0, 0, 0);
    }
    __syncthreads();
  }

  const int col0 = bn + wn + (lane & 15);
  const int row0 = bm + wm + (lane >> 4) * 4;
  #pragma unroll
  for (int ni = 0; ni < NB; ++ni) {
    int col = col0 + ni * 16;
    float bv = (col < nbias) ? bias[col] : 0.f;
    float colsum = 0.f;
    #pragma unroll
    for (int mi = 0; mi < 4; ++mi) {
      #pragma unroll
      for (int j = 0; j < 4; ++j) {
        int row = row0 + mi * 16 + j;
        float v = acc[mi][ni][j] + bv;
        if (EPI == 0) {
          if (RELU) v = v > 0.f ? v : 0.2f * v;
          if (OUTBF16) ((short*)Cout)[(size_t)row * Np + col] = f2bf(v);
          else         ((float*)Cout)[(size_t)row * Np + col] = v;
        } else if (EPI == 1) {
          if (col < 32) {
            aux[(size_t)row * 32 + col] = v;     // vloss
          } else if (col < 160) {
            ((float*)Cout)[(size_t)row * Np + col] = v;
            colsum += v;
          }
        } else { // EPI == 2
          ((float*)Cout)[(size_t)row * Np + col] = v;
          colsum += v;
        }
      }
    }
    if ((EPI == 1 && col >= 32 && col < 160) || EPI == 2) {
      colsum += __shfl_xor(colsum, 16);
      colsum += __shfl_xor(colsum, 32);
      if ((lane >> 4) == 0) {
        int midx = (EPI == 1) ? (col - 32) : col;
        atomicAdd(&meanbuf[(size_t)(bm >> gshift) * 128 + midx], colsum * inv_cnt);
      }
    }
  }
}

// ---------------- merged: pairnorm_c (+state) AND vg/lp/ln gather -> xugb ----------------
__global__ __launch_bounds__(256) void pnc_gather_kernel(
    const float* __restrict__ CD, const float* __restrict__ cmean,
    float* __restrict__ cst, short* __restrict__ xcmb,
    const float* __restrict__ Q, const int* __restrict__ cso, const int* __restrict__ cse,
    const float* __restrict__ clf, const float* __restrict__ vloss,
    short* __restrict__ xugb) {
  int b = blockIdx.x;
  if (b < NCLS / 4) {
    // pairnorm_c: CD stride 192 coloff 32, cmean, write cst + xcmb (bstride 192)
    int wid = threadIdx.x >> 6;
    int lane = threadIdx.x & 63;
    int row = b * 4 + wid;
    int g = row >> 10;           // 1024 rows per graph
    const float* xp = CD + (size_t)row * 192 + 32;
    float y0 = xp[lane]      - cmean[g * 128 + lane];
    float y1 = xp[lane + 64] - cmean[g * 128 + lane + 64];
    float ss = y0 * y0 + y1 * y1;
    #pragma unroll
    for (int o = 32; o > 0; o >>= 1) ss += __shfl_xor(ss, o);
    float inv = rsqrtf(ss * (1.f / 128.f) + 1e-6f);
    float* sp = cst + (size_t)row * 128;
    float s0 = y0 * inv * 0.25f + 0.1f * sp[lane];
    float s1 = y1 * inv * 0.25f + 0.1f * sp[lane + 64];
    sp[lane]      = s0;
    sp[lane + 64] = s1;
    xcmb[(size_t)row * 192 + lane]      = f2bf(s0);
    xcmb[(size_t)row * 192 + lane + 64] = f2bf(s1);
  } else {
    // gather: per (v, m), sum over var's literals
    int t = (b - NCLS / 4) * 256 + threadIdx.x;
    int v = t >> 5, m = t & 31;
    float q = Q[(size_t)v * 32 + m];
    float sig = 1.f / (1.f + expf(-q));
    float vgs = 0.f, lps = 0.f, lns = 0.f;
    int e0 = cso[v], e1 = cso[v + 1];
    for (int e = e0; e < e1; ++e) {
      int ent = cse[e];
      int c = ent >> 1;
      bool pos = ent & 1;
      float clc = clf[(size_t)c * 32 + m];
      vgs -= clc * (sig - (pos ? 0.f : 1.f));
      float vl = vloss[(size_t)c * 32 + m];
      if (pos) lps += vl; else lns += vl;
    }
    short* xp = xugb + (size_t)v * 256 + 128;
    xp[m]      = f2bf(vgs);
    xp[32 + m] = f2bf(lps);
    xp[64 + m] = f2bf(lns);
  }
}

// ---------------- pair_norm + state update + bf16 copy (variables) ----------------
__global__ __launch_bounds__(256) void pairnorm_update_kernel(
    const float* __restrict__ x, int stride, int coloff,
    const float* __restrict__ mean, float* __restrict__ state,
    short* __restrict__ bout, int bstride, int rows_per_g) {
  int wid = threadIdx.x >> 6;
  int lane = threadIdx.x & 63;
  int row = blockIdx.x * 4 + wid;
  int g = row / rows_per_g;
  const float* xp = x + (size_t)row * stride + coloff;
  float y0 = xp[lane]      - mean[g * 128 + lane];
  float y1 = xp[lane + 64] - mean[g * 128 + lane + 64];
  float ss = y0 * y0 + y1 * y1;
  #pragma unroll
  for (int o = 32; o > 0; o >>= 1) ss += __shfl_xor(ss, o);
  float inv = rsqrtf(ss * (1.f / 128.f) + 1e-6f);
  float* sp = state + (size_t)row * 128;
  float s0 = y0 * inv * 0.25f + 0.1f * sp[lane];
  float s1 = y1 * inv * 0.25f + 0.1f * sp[lane + 64];
  sp[lane]      = s0;
  sp[lane + 64] = s1;
  bout[(size_t)row * bstride + lane]      = f2bf(s0);
  bout[(size_t)row * bstride + lane + 64] = f2bf(s1);
}

// ---------------- fused vo MLP: xugb[:, :128] -> logits f32 ----------------
__global__ __launch_bounds__(256) void fused_vo_kernel(
    const short* __restrict__ xugb,
    const short* __restrict__ w0, const short* __restrict__ w1,
    const float* __restrict__ b0, const float* __restrict__ b1,
    const float* __restrict__ w2, const float* __restrict__ b2,
    float* __restrict__ logits) {
  __shared__ short A[64 * 128];
  __shared__ short H1[4][16 * 128];
  __shared__ short H2[4][16 * 128];
  const int wid = threadIdx.x >> 6, lane = threadIdx.x & 63;
  const int rbase = blockIdx.x * 64 + wid * 16;
  #pragma unroll
  for (int i = 0; i < 4; ++i) {
    int s = i * 64 + lane;
    int row = s >> 4, c8 = s & 15;
    *(bf16x8*)&A[(wid * 16 + row) * 128 + c8 * 8] =
        *(const bf16x8*)&xugb[(size_t)(rbase + row) * 256 + c8 * 8];
  }
  const int kof = (lane >> 4) * 8;
  const int l15 = lane & 15;
  f32x4 acc[8] = {};
  #pragma unroll
  for (int ks = 0; ks < 4; ++ks) {
    bf16x8 a = *(const bf16x8*)&A[(wid * 16 + l15) * 128 + ks * 32 + kof];
    #pragma unroll
    for (int ni = 0; ni < 8; ++ni) {
      bf16x8 b = *(const bf16x8*)&w0[(ni * 16 + l15) * 128 + ks * 32 + kof];
      acc[ni] = __builtin_amdgcn_mfma_f32_16x16x32_bf16(a, b, acc[ni], 0, 0, 0);
    }
  }
  #pragma unroll
  for (int ni = 0; ni < 8; ++ni) {
    int col = ni * 16 + l15;
    float bb = b0[col];
    #pragma unroll
    for (int j = 0; j < 4; ++j) {
      float v = acc[ni][j] + bb; v = v > 0.f ? v : 0.2f * v;
      H1[wid][((lane >> 4) * 4 + j) * 128 + col] = f2bf(v);
    }
  }
  f32x4 acc2[8] = {};
  #pragma unroll
  for (int ks = 0; ks < 4; ++ks) {
    bf16x8 a = *(const bf16x8*)&H1[wid][l15 * 128 + ks * 32 + kof];
    #pragma unroll
    for (int ni = 0; ni < 8; ++ni) {
      bf16x8 b = *(const bf16x8*)&w1[(ni * 16 + l15) * 128 + ks * 32 + kof];
      acc2[ni] = __builtin_amdgcn_mfma_f32_16x16x32_bf16(a, b, acc2[ni], 0, 0, 0);
    }
  }
  #pragma unroll
  for (int ni = 0; ni < 8; ++ni) {
    int col = ni * 16 + l15;
    float bb = b1[col];
    #pragma unroll
    for (int j = 0; j < 4; ++j) {
      float v = acc2[ni][j] + bb; v = v > 0.f ? v : 0.2f * v;
      H2[wid][((lane >> 4) * 4 + j) * 128 + col] = f2bf(v);
    }
  }
  {
    int row = lane >> 2, q = lane & 3;
    float s = 0.f;
    #pragma unroll
    for (int jj = 0; jj < 4; ++jj) {
      bf16x8 h = *(const bf16x8*)&H2[wid][row * 128 + q * 32 + jj * 8];
      #pragma unroll
      for (int e = 0; e < 8; ++e) s += bf2f(h[e]) * w2[q * 32 + jj * 8 + e];
    }
    s += __shfl_xor(s, 1);
    s += __shfl_xor(s, 2);
    if (q == 0) logits[rbase + row] = s + b2[0];
  }
}

// ---------------- fused per-clause loss + per-graph sqrt reduce ----------------
__global__ __launch_bounds__(1024) void fused_loss_kernel(
    const float* __restrict__ logits, const int* __restrict__ lit_var,
    const int* __restrict__ lit_sign, float* __restrict__ loss) {
  __shared__ float lg[512];
  __shared__ float red[16];
  int g = blockIdx.x, tid = threadIdx.x;
  if (tid < 512) lg[tid] = logits[(size_t)g * 512 + tid];
  __syncthreads();
  int c = g * 1024 + tid;
  float s = 0.f;
  #pragma unroll
  for (int i = 0; i < 3; ++i) {
    int l = 3 * c + i;
    float sg = (float)lit_sign[l];
    s += softplus_f(lg[lit_var[l] - g * 512] * sg);
  }
  float vv = expf(-s);
  float pcv = vv * (-logf(1.f - vv + 1e-8f));
  #pragma unroll
  for (int o = 32; o > 0; o >>= 1) pcv += __shfl_xor(pcv, o);
  if ((tid & 63) == 0) red[tid >> 6] = pcv;
  __syncthreads();
  if (tid < 16) {
    float x = red[tid];
    #pragma unroll
    for (int o = 8; o > 0; o >>= 1) x += __shfl_xor(x, o);
    if (tid == 0) atomicAdd(loss, sqrtf(x + 1e-6f));
  }
}

__global__ void finalize_kernel(const float* __restrict__ loss_acc, float* __restrict__ out) {
  out[0] = loss_acc[0] * 0.25f;
}

// =======================================================================
extern "C" void kernel_launch(void* const* d_in, const int* in_sizes, int n_in,
                              void* d_out, int out_size, void* d_ws, size_t ws_size,
                              hipStream_t stream) {
  const int* lit_var    = (const int*)d_in[0];
  const int* lit_sign   = (const int*)d_in[1];
  const int* lit_clause = (const int*)d_in[2];
  const float* noise    = (const float*)d_in[5];
  const float* vq_w0 = (const float*)d_in[6];   const float* vq_b0 = (const float*)d_in[7];
  const float* vq_w1 = (const float*)d_in[8];   const float* vq_b1 = (const float*)d_in[9];
  const float* vq_w2 = (const float*)d_in[10];  const float* vq_b2 = (const float*)d_in[11];
  const float* cm_w0 = (const float*)d_in[12];  const float* cm_b0 = (const float*)d_in[13];
  const float* cm_w1 = (const float*)d_in[14];  const float* cm_b1 = (const float*)d_in[15];
  const float* cm_w2 = (const float*)d_in[16];  const float* cm_b2 = (const float*)d_in[17];
  const float* ug_w0 = (const float*)d_in[18];  const float* ug_b0 = (const float*)d_in[19];
  const float* ug_w1 = (const float*)d_in[20];  const float* ug_b1 = (const float*)d_in[21];
  const float* ug_w2 = (const float*)d_in[22];  const float* ug_b2 = (const float*)d_in[23];
  const float* vo_w0 = (const float*)d_in[24];  const float* vo_b0 = (const float*)d_in[25];
  const float* vo_w1 = (const float*)d_in[26];  const float* vo_b1 = (const float*)d_in[27];
  const float* vo_w2 = (const float*)d_in[28];  const float* vo_b2 = (const float*)d_in[29];

  float* ws = (float*)d_ws;
  float* var   = ws + OFF_VAR;
  float* cst   = ws + OFF_CST;
  short* xcmb  = (short*)(ws + OFF_XCMB);
  short* xugb  = (short*)(ws + OFF_XUGB);
  short* bufA  = (short*)(ws + OFF_ABUF);
  short* bufB  = (short*)(ws + OFF_BBUF);
  float* CD    = ws + OFF_CD;
  float* Q     = ws + OFF_Q;
  float* clf   = ws + OFF_CLF;
  float* vloss = ws + OFF_VLOSS;
  float* cmean = ws + OFF_CMEAN;
  float* vmean = ws + OFF_VMEAN;
  float* loss  = ws + OFF_LOSS;
  int*   cso   = (int*)(ws + OFF_CSO);
  int*   cse   = (int*)(ws + OFF_CSE);
  int*   csc   = (int*)(ws + OFF_CSC);
  short* wt    = (short*)(ws + OFF_WT);
  float* logits = (float*)d_out;
  float* loss_out = (float*)d_out + NVARS;

  convert_all_kernel<<<1984, 256, 0, stream>>>(cm_w0, cm_w1, cm_w2, ug_w0, ug_w1, ug_w2,
                                               vo_w0, vo_w1, vq_w0, vq_w1, vq_w2, wt);
  init_state_kernel<<<30784, 256, 0, stream>>>(var, cst, xugb, xcmb, loss, csc);
  csr_count_kernel<<<NLITS / 256, 256, 0, stream>>>(lit_var, csc);
  csr_scan_kernel<<<1, 1024, 0, stream>>>(csc, cso, csc);
  csr_fill_kernel<<<NLITS / 256, 256, 0, stream>>>(lit_var, lit_sign, lit_clause, csc, cse);

  for (int r = 0; r < NROUNDS; ++r) {
    const float* noise_r = noise + (size_t)r * NVARS * 4;

    // vq MLP -> Q
    fused_vq_kernel<<<NVARS / 64, 256, 0, stream>>>(
        xugb, noise_r, wt + WT_VQ0, wt + WT_VQ1, wt + WT_VQ2, vq_b0, vq_b1, vq_b2, Q);

    // clause_val -> clf f32 + xcmb bf16; zero cmean/vmean
    fused_clause_kernel<<<NCLS * 32 / 256, 256, 0, stream>>>(Q, lit_var, lit_sign, xcmb, clf, cmean);

    // cm MLP
    gemm_mfma_kernel<128, true, true, 0><<<dim3(3, NCLS / 128), 256, 0, stream>>>(
        xcmb, 192, wt + WT_CM0, cm_b0, 384, bufA, 384, 192, nullptr, nullptr, 0.f, 0);
    gemm_mfma_kernel<128, true, true, 0><<<dim3(3, NCLS / 128), 256, 0, stream>>>(
        bufA, 384, wt + WT_CM1, cm_b1, 384, bufB, 384, 384, nullptr, nullptr, 0.f, 0);
    gemm_mfma_kernel<64, false, false, 1><<<dim3(3, NCLS / 128), 256, 0, stream>>>(
        bufB, 384, wt + WT_CM2, cm_b2, 160, CD, 192, 384, vloss, cmean, 1.f / 1024.f, 10);

    // pairnorm_c (cst + xcmb) merged with vg/lp/ln gather (-> xugb)
    pnc_gather_kernel<<<NCLS / 4 + NVARS * 32 / 256, 256, 0, stream>>>(
        CD, cmean, cst, xcmb, Q, cso, cse, clf, vloss, xugb);

    // ug MLP
    gemm_mfma_kernel<128, true, true, 0><<<dim3(2, NVARS / 128), 256, 0, stream>>>(
        xugb, 256, wt + WT_UG0, ug_b0, 256, bufA, 256, 256, nullptr, nullptr, 0.f, 0);
    gemm_mfma_kernel<128, true, true, 0><<<dim3(2, NVARS / 128), 256, 0, stream>>>(
        bufA, 256, wt + WT_UG1, ug_b1, 256, bufB, 256, 256, nullptr, nullptr, 0.f, 0);
    gemm_mfma_kernel<64, false, false, 2><<<dim3(2, NVARS / 128), 256, 0, stream>>>(
        bufB, 256, wt + WT_UG2, ug_b2, 128, CD, 128, 256, nullptr, vmean, 1.f / 512.f, 9);

    // variables pair_norm update
    pairnorm_update_kernel<<<NVARS / 4, 256, 0, stream>>>(CD, 128, 0, vmean, var, xugb, 256, 512);

    // vo MLP -> logits
    fused_vo_kernel<<<NVARS / 64, 256, 0, stream>>>(
        xugb, wt + WT_VO0, wt + WT_VO1, vo_b0, vo_b1, vo_w2, vo_b2, logits);

    // loss
    fused_loss_kernel<<<NG, 1024, 0, stream>>>(logits, lit_var, lit_sign, loss);
  }

  finalize_kernel<<<1, 1, 0, stream>>>(loss, loss_out);
}